// Round 3
// baseline (178.635 us; speedup 1.0000x reference)
//
#include <hip/hip_runtime.h>

// DOFEN inference fused pipeline — fp32 I/O, MFMA core.
// Shapes: B=1024, NCOL=NCOND=64, NRODT=1024, D=4, NEST=128, NFOREST=100,
//         NHID=128, NCLASS=10.
//
// Round 10: k_forest wave now owns TWO m-tiles (32 rows) sharing every
// B-fragment load (B operands are m-independent): MFMA per 16B load 2->4,
// B-frag traffic halved, grid 1600->800 (f x 8 bt, 128 rows/block).
// launch_bounds(256,3): VGPR cap ~170 fits accF[2][8]+afr[2][4] (~120 live)
// with NO spill ((256,8) spill disaster = round 8; 48-reg no-pipelining =
// round 9).  LDS 34.8KB/block -> 3 blocks/CU = grid fit 800/256.
// Prep side: revert round-9 merge — k_prep (frag tables + x_t transpose +
// acc zero) + separate k_rodt reading x_t coalesced (round-7 structure).

#define B_      1024
#define NCOL_   64
#define NCOND_  64
#define NRODT_  1024
#define NEST_   128
#define NFOREST_ 100
#define NHID_   128
#define NCLASS_ 10
#define EPS_    1e-5f

typedef __bf16 bf16_t;
typedef bf16_t bf16x8 __attribute__((ext_vector_type(8)));
typedef float  f32x4  __attribute__((ext_vector_type(4)));

#define MFMA16(a,b,c) __builtin_amdgcn_mfma_f32_16x16x32_bf16(a,b,c,0,0,0)

#define EG_FRAGS   (NFOREST_*4*8*64)   // 204800 frag-rows of 8 bf16
#define W1_FRAGS   (4*8*64)            // 2048
#define L2_FRAGS   (4*64)              // 256

#define ZLD 136                        // bf16 z-tile row pad: 272B, 16B-aligned

// ---------------------------------------------------------------------------
// k_prep: B-fragment tables (Esel/f, lin1w, lin2w hi/lo) + x_t + acc zero.
// blocks: [0,800) Esel  [800,808) lin1w  [808] lin2w  [809,1065) x_t
//         [1065,1105) acc-zero.   grid = 1105 x 256.
// ---------------------------------------------------------------------------
__global__ __launch_bounds__(256) void k_prep(
    const float* __restrict__ E,     const int*   __restrict__ swr,
    const float* __restrict__ lin1w, const float* __restrict__ lin2w,
    const float* __restrict__ x,
    bf16_t* __restrict__ Eh,  bf16_t* __restrict__ El,
    bf16_t* __restrict__ Wh,  bf16_t* __restrict__ Wl,
    bf16_t* __restrict__ L2h, bf16_t* __restrict__ L2l,
    float*  __restrict__ x_t, float* __restrict__ accz)
{
    int blk = blockIdx.x, tid = threadIdx.x;
    if (blk < 800) {                              // Esel frags: t=(((f*4+kk)*8+nn)*64+lane)
        int t = blk * 256 + tid;
        int lane = t & 63, nn = (t >> 6) & 7, kk = (t >> 9) & 3, f = t >> 11;
        int q = lane >> 4, n = nn * 16 + (lane & 15);
        bf16x8 hi, lo;
#pragma unroll
        for (int j = 0; j < 8; ++j) {
            int e = kk * 32 + q * 8 + j;
            int r = swr[f * NEST_ + e];
            float v = E[r * NHID_ + n];
            bf16_t h = (bf16_t)v;
            hi[j] = h; lo[j] = (bf16_t)(v - (float)h);
        }
        *(bf16x8*)(Eh + (size_t)t * 8) = hi;
        *(bf16x8*)(El + (size_t)t * 8) = lo;
    } else if (blk < 808) {                       // lin1w frags: t=(kk*8+nn)*64+lane
        int t = (blk - 800) * 256 + tid;
        int lane = t & 63, nn = (t >> 6) & 7, kk = t >> 9;
        int q = lane >> 4, n = nn * 16 + (lane & 15);
        bf16x8 hi, lo;
#pragma unroll
        for (int j = 0; j < 8; ++j) {
            int k = kk * 32 + q * 8 + j;
            float v = lin1w[k * NHID_ + n];
            bf16_t h = (bf16_t)v;
            hi[j] = h; lo[j] = (bf16_t)(v - (float)h);
        }
        *(bf16x8*)(Wh + t * 8) = hi;
        *(bf16x8*)(Wl + t * 8) = lo;
    } else if (blk == 808) {                      // lin2w frags (N pad 16): t=kk*64+lane
        int t = tid;
        int lane = t & 63, kk = t >> 6;
        int q = lane >> 4, n = lane & 15;
        bf16x8 hi, lo;
#pragma unroll
        for (int j = 0; j < 8; ++j) {
            int k = kk * 32 + q * 8 + j;
            float v = (n < NCLASS_) ? lin2w[k * NCLASS_ + n] : 0.f;
            bf16_t h = (bf16_t)v;
            hi[j] = h; lo[j] = (bf16_t)(v - (float)h);
        }
        *(bf16x8*)(L2h + t * 8) = hi;
        *(bf16x8*)(L2l + t * 8) = lo;
    } else if (blk < 1065) {                      // x_t[col][b] = x[b][col]
        int t = (blk - 809) * 256 + tid;
        x_t[t] = x[(t & 1023) * NCOL_ + (t >> 10)];
    } else {                                      // zero acc (B*NCLASS = 10240)
        int t = (blk - 1065) * 256 + tid;
        if (t < B_ * NCLASS_) accz[t] = 0.f;
    }
}

// ---------------------------------------------------------------------------
// k_rodt: one g per block (params scalar-uniform); thread handles 4 b's.
// ---------------------------------------------------------------------------
__global__ __launch_bounds__(256) void k_rodt(
    const float* __restrict__ x_t,  const float* __restrict__ w1,
    const float* __restrict__ b1,   const int*  __restrict__ perm,
    const float* __restrict__ gn1g, const float* __restrict__ gn1b,
    const float* __restrict__ w2a,  const float* __restrict__ b2a,
    const float* __restrict__ gn2g, const float* __restrict__ gn2b,
    const float* __restrict__ w2b,  const float* __restrict__ b2b,
    float* __restrict__ w_t)
{
    int g  = blockIdx.x;
    int bq = threadIdx.x * 4;

    int4 p4 = ((const int4*)perm)[g];
    int col[4]  = { p4.x & 63, p4.y & 63, p4.z & 63, p4.w & 63 };
    int cond[4] = { p4.x >> 6, p4.y >> 6, p4.z >> 6, p4.w >> 6 };
    float w1v[4], b1v[4];
#pragma unroll
    for (int j = 0; j < 4; ++j) {
        w1v[j] = w1[col[j] * NCOND_ + cond[j]];
        b1v[j] = b1[col[j] * NCOND_ + cond[j]];
    }
    float4 g1  = ((const float4*)gn1g)[g];
    float4 o1  = ((const float4*)gn1b)[g];
    float4 ba  = ((const float4*)b2a)[g];
    float4 g2  = ((const float4*)gn2g)[g];
    float4 o2  = ((const float4*)gn2b)[g];
    float4 wb4 = ((const float4*)w2b)[g];
    float  bb  = b2b[g];
    float4 wa[4];
    const float4* w2a4 = (const float4*)w2a;
#pragma unroll
    for (int i = 0; i < 4; ++i) wa[i] = w2a4[g * 4 + i];

    float xv[4][4];
#pragma unroll
    for (int j = 0; j < 4; ++j) {
        float4 t = *(const float4*)&x_t[col[j] * B_ + bq];
        xv[j][0] = t.x; xv[j][1] = t.y; xv[j][2] = t.z; xv[j][3] = t.w;
    }

    float outv[4];
#pragma unroll
    for (int bi = 0; bi < 4; ++bi) {
        float v[4];
#pragma unroll
        for (int j = 0; j < 4; ++j) {
            float t = xv[j][bi] * w1v[j] + b1v[j];
            v[j] = 1.0f / (1.0f + __expf(-t));
        }
        float mu = (v[0] + v[1] + v[2] + v[3]) * 0.25f;
        float var = 0.f;
#pragma unroll
        for (int j = 0; j < 4; ++j) { float d = v[j] - mu; var += d * d; }
        var *= 0.25f;
        float rs = rsqrtf(var + EPS_);
        float h[4];
        h[0] = (v[0] - mu) * rs * g1.x + o1.x;
        h[1] = (v[1] - mu) * rs * g1.y + o1.y;
        h[2] = (v[2] - mu) * rs * g1.z + o1.z;
        h[3] = (v[3] - mu) * rs * g1.w + o1.w;

        float4 a = ba;
#pragma unroll
        for (int i = 0; i < 4; ++i) {
            a.x += h[i] * wa[i].x; a.y += h[i] * wa[i].y;
            a.z += h[i] * wa[i].z; a.w += h[i] * wa[i].w;
        }
        float t2[4];
        t2[0] = fmaxf(a.x, 0.f); t2[1] = fmaxf(a.y, 0.f);
        t2[2] = fmaxf(a.z, 0.f); t2[3] = fmaxf(a.w, 0.f);

        float mu2 = (t2[0] + t2[1] + t2[2] + t2[3]) * 0.25f;
        float var2 = 0.f;
#pragma unroll
        for (int j = 0; j < 4; ++j) { float d = t2[j] - mu2; var2 += d * d; }
        var2 *= 0.25f;
        float rs2 = rsqrtf(var2 + EPS_);

        float wvv = bb;
        wvv += ((t2[0] - mu2) * rs2 * g2.x + o2.x) * wb4.x;
        wvv += ((t2[1] - mu2) * rs2 * g2.y + o2.y) * wb4.y;
        wvv += ((t2[2] - mu2) * rs2 * g2.z + o2.z) * wb4.z;
        wvv += ((t2[3] - mu2) * rs2 * g2.w + o2.w) * wb4.w;
        outv[bi] = wvv;
    }
    *(float4*)&w_t[(size_t)g * B_ + bq] = make_float4(outv[0], outv[1], outv[2], outv[3]);
}

// ---------------------------------------------------------------------------
// k_forest: block=(f, 128 rows), 4 waves, wave = TWO m-tiles (32 rows) x all
// 8 n-tiles; every B-fragment load feeds 4 MFMAs.  Barrier-free; per-wave
// 32xZLD bf16 LDS z-tile.  lane: q=lane>>4, mc=lane&15.  A: m=mc,
// k=q*8+j(+32kk).  C: row=q*4+reg, col=nn*16+mc.
// ---------------------------------------------------------------------------
__global__ __launch_bounds__(256, 3) void k_forest(
    const float*  __restrict__ w_t, const int* __restrict__ swr,
    const bf16_t* __restrict__ Eh,  const bf16_t* __restrict__ El,
    const bf16_t* __restrict__ Wh,  const bf16_t* __restrict__ Wl,
    const bf16_t* __restrict__ L2h, const bf16_t* __restrict__ L2l,
    const float* __restrict__ ln1g, const float* __restrict__ ln1b,
    const float* __restrict__ lin1b,
    const float* __restrict__ ln2g, const float* __restrict__ ln2b,
    float* __restrict__ acc)
{
    __shared__ __align__(16) bf16_t zsh[4][32 * ZLD];   // per-wave 2-tile z

    int tid  = threadIdx.x;
    int wid  = tid >> 6;
    int lane = tid & 63;
    int q    = lane >> 4;
    int mc   = lane & 15;

    int n    = blockIdx.x;
    int swiz = (n & 7) * 100 + (n >> 3);  // co-locate same-f blocks per XCD
    int f    = swiz >> 3;
    int bt   = swiz & 7;
    int b0   = bt * 128 + wid * 32;       // wave rows [b0, b0+32)

    const int* swrf = swr + f * NEST_;
    bf16_t* zw = zsh[wid];

    // ---- softmax, both m-tiles: ws[m][e=kk*32+q*8+j] ----
    float ex[2][4][8];
    float mx0 = -1e30f, mx1 = -1e30f;
#pragma unroll
    for (int kk = 0; kk < 4; ++kk) {
        int4 r0 = *(const int4*)(swrf + kk * 32 + q * 8);
        int4 r1 = *(const int4*)(swrf + kk * 32 + q * 8 + 4);
        int rr[8] = { r0.x, r0.y, r0.z, r0.w, r1.x, r1.y, r1.z, r1.w };
#pragma unroll
        for (int j = 0; j < 8; ++j) {
            const float* wp = w_t + (size_t)rr[j] * B_ + b0 + mc;
            float v0 = wp[0];
            float v1 = wp[16];
            ex[0][kk][j] = v0; mx0 = fmaxf(mx0, v0);
            ex[1][kk][j] = v1; mx1 = fmaxf(mx1, v1);
        }
    }
    mx0 = fmaxf(mx0, __shfl_xor(mx0, 16)); mx0 = fmaxf(mx0, __shfl_xor(mx0, 32));
    mx1 = fmaxf(mx1, __shfl_xor(mx1, 16)); mx1 = fmaxf(mx1, __shfl_xor(mx1, 32));
    float s0 = 0.f, s1 = 0.f;
#pragma unroll
    for (int kk = 0; kk < 4; ++kk)
#pragma unroll
        for (int j = 0; j < 8; ++j) {
            ex[0][kk][j] = __expf(ex[0][kk][j] - mx0); s0 += ex[0][kk][j];
            ex[1][kk][j] = __expf(ex[1][kk][j] - mx1); s1 += ex[1][kk][j];
        }
    s0 += __shfl_xor(s0, 16); s0 += __shfl_xor(s0, 32);
    s1 += __shfl_xor(s1, 16); s1 += __shfl_xor(s1, 32);
    float inv0 = 1.f / s0, inv1 = 1.f / s1;

    bf16x8 afr[2][4];
#pragma unroll
    for (int kk = 0; kk < 4; ++kk)
#pragma unroll
        for (int j = 0; j < 8; ++j) {
            afr[0][kk][j] = (bf16_t)(ex[0][kk][j] * inv0);
            afr[1][kk][j] = (bf16_t)(ex[1][kk][j] * inv1);
        }

    // ---- F-GEMM: 8 n-tiles, K=128, B split hi/lo, shared across 2 m ----
    f32x4 accF[2][8];
#pragma unroll
    for (int t = 0; t < 2; ++t)
#pragma unroll
        for (int nn = 0; nn < 8; ++nn) accF[t][nn] = (f32x4){0.f, 0.f, 0.f, 0.f};
    const bf16x8* EHf = (const bf16x8*)Eh;
    const bf16x8* ELf = (const bf16x8*)El;
#pragma unroll
    for (int kk = 0; kk < 4; ++kk) {
        size_t bi = (size_t)(f * 4 + kk) * 8;
#pragma unroll
        for (int nn = 0; nn < 8; ++nn) {
            bf16x8 bh = EHf[(bi + nn) * 64 + lane];
            bf16x8 bl = ELf[(bi + nn) * 64 + lane];
            accF[0][nn] = MFMA16(afr[0][kk], bh, accF[0][nn]);
            accF[1][nn] = MFMA16(afr[1][kk], bh, accF[1][nn]);
            accF[0][nn] = MFMA16(afr[0][kk], bl, accF[0][nn]);
            accF[1][nn] = MFMA16(afr[1][kk], bl, accF[1][nn]);
        }
    }

    // ---- LayerNorm 1 (wave-internal): rows t*16+q*4+reg, store bf16 ----
    float mu[2][4], rs[2][4];
#pragma unroll
    for (int t = 0; t < 2; ++t)
#pragma unroll
        for (int reg = 0; reg < 4; ++reg) {
            float ps = 0.f, pq = 0.f;
#pragma unroll
            for (int nn = 0; nn < 8; ++nn) { float v = accF[t][nn][reg]; ps += v; pq += v * v; }
#pragma unroll
            for (int o = 1; o <= 8; o <<= 1) { ps += __shfl_xor(ps, o); pq += __shfl_xor(pq, o); }
            float m_ = ps * (1.f / NHID_);
            mu[t][reg] = m_;
            rs[t][reg] = rsqrtf(pq * (1.f / NHID_) - m_ * m_ + EPS_);
        }
#pragma unroll
    for (int nn = 0; nn < 8; ++nn) {
        int c = nn * 16 + mc;
        float gv = ln1g[c], bv = ln1b[c];
#pragma unroll
        for (int t = 0; t < 2; ++t)
#pragma unroll
            for (int reg = 0; reg < 4; ++reg)
                zw[(t * 16 + q * 4 + reg) * ZLD + c] =
                    (bf16_t)((accF[t][nn][reg] - mu[t][reg]) * rs[t][reg] * gv + bv);
    }

    // ---- lin1 GEMM: A direct bf16x8 from zw, B = Wh/Wl shared across 2 m --
    bf16x8 a2[2][4];
#pragma unroll
    for (int t = 0; t < 2; ++t)
#pragma unroll
        for (int kk = 0; kk < 4; ++kk)
            a2[t][kk] = *(const bf16x8*)&zw[(t * 16 + mc) * ZLD + kk * 32 + q * 8];

    f32x4 accA[2][8];
#pragma unroll
    for (int t = 0; t < 2; ++t)
#pragma unroll
        for (int nn = 0; nn < 8; ++nn) accA[t][nn] = (f32x4){0.f, 0.f, 0.f, 0.f};
    const bf16x8* WHf = (const bf16x8*)Wh;
    const bf16x8* WLf = (const bf16x8*)Wl;
#pragma unroll
    for (int kk = 0; kk < 4; ++kk) {
#pragma unroll
        for (int nn = 0; nn < 8; ++nn) {
            bf16x8 bh = WHf[(kk * 8 + nn) * 64 + lane];
            bf16x8 bl = WLf[(kk * 8 + nn) * 64 + lane];
            accA[0][nn] = MFMA16(a2[0][kk], bh, accA[0][nn]);
            accA[1][nn] = MFMA16(a2[1][kk], bh, accA[1][nn]);
            accA[0][nn] = MFMA16(a2[0][kk], bl, accA[0][nn]);
            accA[1][nn] = MFMA16(a2[1][kk], bl, accA[1][nn]);
        }
    }

    // ---- bias + ReLU + LayerNorm 2 (wave-internal) ----
#pragma unroll
    for (int nn = 0; nn < 8; ++nn) {
        float bv = lin1b[nn * 16 + mc];
#pragma unroll
        for (int t = 0; t < 2; ++t)
#pragma unroll
            for (int reg = 0; reg < 4; ++reg)
                accA[t][nn][reg] = fmaxf(accA[t][nn][reg] + bv, 0.f);
    }
    float mu2[2][4], rs2[2][4];
#pragma unroll
    for (int t = 0; t < 2; ++t)
#pragma unroll
        for (int reg = 0; reg < 4; ++reg) {
            float ps = 0.f, pq = 0.f;
#pragma unroll
            for (int nn = 0; nn < 8; ++nn) { float v = accA[t][nn][reg]; ps += v; pq += v * v; }
#pragma unroll
            for (int o = 1; o <= 8; o <<= 1) { ps += __shfl_xor(ps, o); pq += __shfl_xor(pq, o); }
            float m_ = ps * (1.f / NHID_);
            mu2[t][reg] = m_;
            rs2[t][reg] = rsqrtf(pq * (1.f / NHID_) - m_ * m_ + EPS_);
        }
#pragma unroll
    for (int nn = 0; nn < 8; ++nn) {
        int c = nn * 16 + mc;
        float gv = ln2g[c], bv = ln2b[c];
#pragma unroll
        for (int t = 0; t < 2; ++t)
#pragma unroll
            for (int reg = 0; reg < 4; ++reg)
                zw[(t * 16 + q * 4 + reg) * ZLD + c] =
                    (bf16_t)((accA[t][nn][reg] - mu2[t][reg]) * rs2[t][reg] * gv + bv);
    }

    // ---- lin2: 16x128 @ 128x16(padded), B shared across 2 m ----
    f32x4 accO[2] = { (f32x4){0.f,0.f,0.f,0.f}, (f32x4){0.f,0.f,0.f,0.f} };
    const bf16x8* LHf = (const bf16x8*)L2h;
    const bf16x8* LLf = (const bf16x8*)L2l;
#pragma unroll
    for (int kk = 0; kk < 4; ++kk) {
        bf16x8 lh = LHf[kk * 64 + lane];
        bf16x8 ll = LLf[kk * 64 + lane];
#pragma unroll
        for (int t = 0; t < 2; ++t) {
            bf16x8 a3 = *(const bf16x8*)&zw[(t * 16 + mc) * ZLD + kk * 32 + q * 8];
            accO[t] = MFMA16(a3, lh, accO[t]);
            accO[t] = MFMA16(a3, ll, accO[t]);
        }
    }
    if (mc < NCLASS_) {
#pragma unroll
        for (int t = 0; t < 2; ++t)
#pragma unroll
            for (int reg = 0; reg < 4; ++reg)
                atomicAdd(&acc[(b0 + t * 16 + q * 4 + reg) * NCLASS_ + mc], accO[t][reg]);
    }
}

// ---------------------------------------------------------------------------
// k_final: out = acc/NFOREST + lin2_b
// ---------------------------------------------------------------------------
__global__ __launch_bounds__(256) void k_final(
    const float* __restrict__ acc, const float* __restrict__ lin2b,
    float* __restrict__ out)
{
    int i = blockIdx.x * 256 + threadIdx.x;
    if (i < B_ * NCLASS_) {
        int c = i % NCLASS_;
        out[i] = acc[i] * (1.f / NFOREST_) + lin2b[c];
    }
}

// ---------------------------------------------------------------------------
extern "C" void kernel_launch(void* const* d_in, const int* in_sizes, int n_in,
                              void* d_out, int out_size, void* d_ws, size_t ws_size,
                              hipStream_t stream)
{
    const float* x     = (const float*)d_in[0];
    const float* w1    = (const float*)d_in[1];
    const float* b1    = (const float*)d_in[2];
    const int*   perm  = (const int*)  d_in[3];
    const float* gn1g  = (const float*)d_in[4];
    const float* gn1b  = (const float*)d_in[5];
    const float* w2a   = (const float*)d_in[6];
    const float* b2a   = (const float*)d_in[7];
    const float* gn2g  = (const float*)d_in[8];
    const float* gn2b  = (const float*)d_in[9];
    const float* w2b   = (const float*)d_in[10];
    const float* b2b   = (const float*)d_in[11];
    const float* E     = (const float*)d_in[12];
    const int*   swr   = (const int*)  d_in[13];
    const float* ln1g  = (const float*)d_in[14];
    const float* ln1b  = (const float*)d_in[15];
    const float* lin1w = (const float*)d_in[16];
    const float* lin1b = (const float*)d_in[17];
    const float* ln2g  = (const float*)d_in[18];
    const float* ln2b  = (const float*)d_in[19];
    const float* lin2w = (const float*)d_in[20];
    const float* lin2b = (const float*)d_in[21];

    char* base = (char*)d_ws;
    float*  w_t  = (float*)base;                                    // 4 MB
    float*  accp = (float*)(base + 4u * 1024 * 1024);               // 40 KB
    float*  x_t  = (float*)(base + 4u * 1024 * 1024 + 64 * 1024);   // 256 KB
    bf16_t* Eh   = (bf16_t*)(base + 4u * 1024 * 1024 + 64 * 1024 + 256 * 1024);
    bf16_t* El   = Eh  + (size_t)EG_FRAGS * 8;
    bf16_t* Wh   = El  + (size_t)EG_FRAGS * 8;
    bf16_t* Wl   = Wh  + (size_t)W1_FRAGS * 8;
    bf16_t* L2h  = Wl  + (size_t)W1_FRAGS * 8;
    bf16_t* L2l  = L2h + (size_t)L2_FRAGS * 8;

    k_prep<<<1105, 256, 0, stream>>>(E, swr, lin1w, lin2w, x,
                                     Eh, El, Wh, Wl, L2h, L2l, x_t, accp);

    k_rodt<<<NRODT_, 256, 0, stream>>>(
        x_t, w1, b1, perm, gn1g, gn1b, w2a, b2a, gn2g, gn2b, w2b, b2b, w_t);

    k_forest<<<NFOREST_ * 8, 256, 0, stream>>>(
        w_t, swr, Eh, El, Wh, Wl, L2h, L2l,
        ln1g, ln1b, lin1b, ln2g, ln2b, accp);

    k_final<<<(B_ * NCLASS_ + 255) / 256, 256, 0, stream>>>(
        accp, lin2b, (float*)d_out);
}

// Round 4
// 158.861 us; speedup vs baseline: 1.1245x; 1.1245x over previous
//
#include <hip/hip_runtime.h>

// DOFEN inference fused pipeline — fp32 I/O, MFMA core.
// Shapes: B=1024, NCOL=NCOND=64, NRODT=1024, D=4, NEST=128, NFOREST=100,
//         NHID=128, NCLASS=10.
//
// Round 11: k_forest rebuilt around LDS staging (§5 anatomy).  Block = 512
// threads (8 waves x 16 rows = 128 rows), grid 800.  E-frags (64 KB, forest-
// dependent) + W-frags (64 KB, shared) staged once per block via
// global_load_lds(16B) and ds_read_b128 by all 8 waves: L2 traffic 8x down,
// dependent-load latency becomes bulk DMA drained at one barrier.
// bufE is reused after the post-F barrier for the z-tile (34.8 KB) and the
// staged lin2 frags (8 KB @ +40960).  LDS = 128 KB -> 1 block/CU, 2
// waves/SIMD.  Staged bytes are bit-identical copies; MFMA order unchanged.
// k_prep / k_rodt / k_final = verified round-7 versions (x_t transpose).

#define B_      1024
#define NCOL_   64
#define NCOND_  64
#define NRODT_  1024
#define NEST_   128
#define NFOREST_ 100
#define NHID_   128
#define NCLASS_ 10
#define EPS_    1e-5f

typedef __bf16 bf16_t;
typedef bf16_t bf16x8 __attribute__((ext_vector_type(8)));
typedef float  f32x4  __attribute__((ext_vector_type(4)));

#define MFMA16(a,b,c) __builtin_amdgcn_mfma_f32_16x16x32_bf16(a,b,c,0,0,0)

#define EG_FRAGS   (NFOREST_*4*8*64)   // 204800 frag-rows of 8 bf16
#define W1_FRAGS   (4*8*64)            // 2048
#define L2_FRAGS   (4*64)              // 256

#define ZLD 136                        // bf16 z-tile row pad: 272B, 16B-aligned

// global(16B/lane) -> LDS DMA; LDS dest = uniform base + lane*16.
#define GLDS16(gp, lp) \
    __builtin_amdgcn_global_load_lds( \
        (const __attribute__((address_space(1))) unsigned int*)(gp), \
        (__attribute__((address_space(3))) unsigned int*)(lp), 16, 0, 0)

// ---------------------------------------------------------------------------
// k_prep: B-fragment tables (Esel/f, lin1w, lin2w hi/lo) + x_t + acc zero.
// blocks: [0,800) Esel  [800,808) lin1w  [808] lin2w  [809,1065) x_t
//         [1065,1105) acc-zero.   grid = 1105 x 256.
// ---------------------------------------------------------------------------
__global__ __launch_bounds__(256) void k_prep(
    const float* __restrict__ E,     const int*   __restrict__ swr,
    const float* __restrict__ lin1w, const float* __restrict__ lin2w,
    const float* __restrict__ x,
    bf16_t* __restrict__ Eh,  bf16_t* __restrict__ El,
    bf16_t* __restrict__ Wh,  bf16_t* __restrict__ Wl,
    bf16_t* __restrict__ L2h, bf16_t* __restrict__ L2l,
    float*  __restrict__ x_t, float* __restrict__ accz)
{
    int blk = blockIdx.x, tid = threadIdx.x;
    if (blk < 800) {                              // Esel frags: t=(((f*4+kk)*8+nn)*64+lane)
        int t = blk * 256 + tid;
        int lane = t & 63, nn = (t >> 6) & 7, kk = (t >> 9) & 3, f = t >> 11;
        int q = lane >> 4, n = nn * 16 + (lane & 15);
        bf16x8 hi, lo;
#pragma unroll
        for (int j = 0; j < 8; ++j) {
            int e = kk * 32 + q * 8 + j;
            int r = swr[f * NEST_ + e];
            float v = E[r * NHID_ + n];
            bf16_t h = (bf16_t)v;
            hi[j] = h; lo[j] = (bf16_t)(v - (float)h);
        }
        *(bf16x8*)(Eh + (size_t)t * 8) = hi;
        *(bf16x8*)(El + (size_t)t * 8) = lo;
    } else if (blk < 808) {                       // lin1w frags: t=(kk*8+nn)*64+lane
        int t = (blk - 800) * 256 + tid;
        int lane = t & 63, nn = (t >> 6) & 7, kk = t >> 9;
        int q = lane >> 4, n = nn * 16 + (lane & 15);
        bf16x8 hi, lo;
#pragma unroll
        for (int j = 0; j < 8; ++j) {
            int k = kk * 32 + q * 8 + j;
            float v = lin1w[k * NHID_ + n];
            bf16_t h = (bf16_t)v;
            hi[j] = h; lo[j] = (bf16_t)(v - (float)h);
        }
        *(bf16x8*)(Wh + t * 8) = hi;
        *(bf16x8*)(Wl + t * 8) = lo;
    } else if (blk == 808) {                      // lin2w frags (N pad 16): t=kk*64+lane
        int t = tid;
        int lane = t & 63, kk = t >> 6;
        int q = lane >> 4, n = lane & 15;
        bf16x8 hi, lo;
#pragma unroll
        for (int j = 0; j < 8; ++j) {
            int k = kk * 32 + q * 8 + j;
            float v = (n < NCLASS_) ? lin2w[k * NCLASS_ + n] : 0.f;
            bf16_t h = (bf16_t)v;
            hi[j] = h; lo[j] = (bf16_t)(v - (float)h);
        }
        *(bf16x8*)(L2h + t * 8) = hi;
        *(bf16x8*)(L2l + t * 8) = lo;
    } else if (blk < 1065) {                      // x_t[col][b] = x[b][col]
        int t = (blk - 809) * 256 + tid;
        x_t[t] = x[(t & 1023) * NCOL_ + (t >> 10)];
    } else {                                      // zero acc (B*NCLASS = 10240)
        int t = (blk - 1065) * 256 + tid;
        if (t < B_ * NCLASS_) accz[t] = 0.f;
    }
}

// ---------------------------------------------------------------------------
// k_rodt: one g per block (params scalar-uniform); thread handles 4 b's.
// ---------------------------------------------------------------------------
__global__ __launch_bounds__(256) void k_rodt(
    const float* __restrict__ x_t,  const float* __restrict__ w1,
    const float* __restrict__ b1,   const int*  __restrict__ perm,
    const float* __restrict__ gn1g, const float* __restrict__ gn1b,
    const float* __restrict__ w2a,  const float* __restrict__ b2a,
    const float* __restrict__ gn2g, const float* __restrict__ gn2b,
    const float* __restrict__ w2b,  const float* __restrict__ b2b,
    float* __restrict__ w_t)
{
    int g  = blockIdx.x;
    int bq = threadIdx.x * 4;

    int4 p4 = ((const int4*)perm)[g];
    int col[4]  = { p4.x & 63, p4.y & 63, p4.z & 63, p4.w & 63 };
    int cond[4] = { p4.x >> 6, p4.y >> 6, p4.z >> 6, p4.w >> 6 };
    float w1v[4], b1v[4];
#pragma unroll
    for (int j = 0; j < 4; ++j) {
        w1v[j] = w1[col[j] * NCOND_ + cond[j]];
        b1v[j] = b1[col[j] * NCOND_ + cond[j]];
    }
    float4 g1  = ((const float4*)gn1g)[g];
    float4 o1  = ((const float4*)gn1b)[g];
    float4 ba  = ((const float4*)b2a)[g];
    float4 g2  = ((const float4*)gn2g)[g];
    float4 o2  = ((const float4*)gn2b)[g];
    float4 wb4 = ((const float4*)w2b)[g];
    float  bb  = b2b[g];
    float4 wa[4];
    const float4* w2a4 = (const float4*)w2a;
#pragma unroll
    for (int i = 0; i < 4; ++i) wa[i] = w2a4[g * 4 + i];

    float xv[4][4];
#pragma unroll
    for (int j = 0; j < 4; ++j) {
        float4 t = *(const float4*)&x_t[col[j] * B_ + bq];
        xv[j][0] = t.x; xv[j][1] = t.y; xv[j][2] = t.z; xv[j][3] = t.w;
    }

    float outv[4];
#pragma unroll
    for (int bi = 0; bi < 4; ++bi) {
        float v[4];
#pragma unroll
        for (int j = 0; j < 4; ++j) {
            float t = xv[j][bi] * w1v[j] + b1v[j];
            v[j] = 1.0f / (1.0f + __expf(-t));
        }
        float mu = (v[0] + v[1] + v[2] + v[3]) * 0.25f;
        float var = 0.f;
#pragma unroll
        for (int j = 0; j < 4; ++j) { float d = v[j] - mu; var += d * d; }
        var *= 0.25f;
        float rs = rsqrtf(var + EPS_);
        float h[4];
        h[0] = (v[0] - mu) * rs * g1.x + o1.x;
        h[1] = (v[1] - mu) * rs * g1.y + o1.y;
        h[2] = (v[2] - mu) * rs * g1.z + o1.z;
        h[3] = (v[3] - mu) * rs * g1.w + o1.w;

        float4 a = ba;
#pragma unroll
        for (int i = 0; i < 4; ++i) {
            a.x += h[i] * wa[i].x; a.y += h[i] * wa[i].y;
            a.z += h[i] * wa[i].z; a.w += h[i] * wa[i].w;
        }
        float t2[4];
        t2[0] = fmaxf(a.x, 0.f); t2[1] = fmaxf(a.y, 0.f);
        t2[2] = fmaxf(a.z, 0.f); t2[3] = fmaxf(a.w, 0.f);

        float mu2 = (t2[0] + t2[1] + t2[2] + t2[3]) * 0.25f;
        float var2 = 0.f;
#pragma unroll
        for (int j = 0; j < 4; ++j) { float d = t2[j] - mu2; var2 += d * d; }
        var2 *= 0.25f;
        float rs2 = rsqrtf(var2 + EPS_);

        float wvv = bb;
        wvv += ((t2[0] - mu2) * rs2 * g2.x + o2.x) * wb4.x;
        wvv += ((t2[1] - mu2) * rs2 * g2.y + o2.y) * wb4.y;
        wvv += ((t2[2] - mu2) * rs2 * g2.z + o2.z) * wb4.z;
        wvv += ((t2[3] - mu2) * rs2 * g2.w + o2.w) * wb4.w;
        outv[bi] = wvv;
    }
    *(float4*)&w_t[(size_t)g * B_ + bq] = make_float4(outv[0], outv[1], outv[2], outv[3]);
}

// ---------------------------------------------------------------------------
// k_forest: block = (f, 128 rows), 8 waves x 16-row m-tile, grid 800 x 512.
// Stage E/W frag tables into LDS once per block (global_load_lds, linear
// copy in lane-consumption order), all waves ds_read_b128 them.
// bufE layout: [0,32K) Eh rows, [32K,64K) El rows; after post-F barrier:
// [0,34816) per-wave z tiles, [40960,49152) staged lin2 frags.
// lane: q=lane>>4, mc=lane&15.  A: m=mc, k=q*8+j(+32kk).
// C: row=q*4+reg, col=nn*16+mc.
// ---------------------------------------------------------------------------
__global__ __launch_bounds__(512, 2) void k_forest(
    const float*  __restrict__ w_t, const int* __restrict__ swr,
    const bf16_t* __restrict__ Eh,  const bf16_t* __restrict__ El,
    const bf16_t* __restrict__ Wh,  const bf16_t* __restrict__ Wl,
    const bf16_t* __restrict__ L2h, const bf16_t* __restrict__ L2l,
    const float* __restrict__ ln1g, const float* __restrict__ ln1b,
    const float* __restrict__ lin1b,
    const float* __restrict__ ln2g, const float* __restrict__ ln2b,
    float* __restrict__ acc)
{
    __shared__ __align__(16) char bufE[65536];
    __shared__ __align__(16) char bufW[65536];

    int tid  = threadIdx.x;
    int wid  = tid >> 6;
    int lane = tid & 63;
    int q    = lane >> 4;
    int mc   = lane & 15;

    int n    = blockIdx.x;                 // [0,800)
    int lin  = (n & 7) * 100 + (n >> 3);   // co-locate same-f blocks per XCD
    int f    = lin >> 3;
    int bt   = lin & 7;
    int b0   = bt * 128 + wid * 16;        // this wave's first batch row

    const int* swrf = swr + f * NEST_;

    // ---- stage E (forest f) + W frag tables: 16 x 1KB rows per wave ----
    {
        const char* Ehp = (const char*)Eh + (size_t)f * 32 * 1024;
        const char* Elp = (const char*)El + (size_t)f * 32 * 1024;
        const char* Whp = (const char*)Wh;
        const char* Wlp = (const char*)Wl;
#pragma unroll
        for (int c = 0; c < 4; ++c) {
            int r = wid * 4 + c;           // rows 0..31 across 8 waves
            GLDS16(Ehp + r * 1024 + lane * 16, bufE + r * 1024);
            GLDS16(Elp + r * 1024 + lane * 16, bufE + 32768 + r * 1024);
            GLDS16(Whp + r * 1024 + lane * 16, bufW + r * 1024);
            GLDS16(Wlp + r * 1024 + lane * 16, bufW + 32768 + r * 1024);
        }
    }

    // ---- softmax in A-frag lanes: ws[m=mc][e=kk*32+q*8+j] ----
    float ex[4][8];
    float mx = -1e30f;
#pragma unroll
    for (int kk = 0; kk < 4; ++kk) {
        int4 r0 = *(const int4*)(swrf + kk * 32 + q * 8);
        int4 r1 = *(const int4*)(swrf + kk * 32 + q * 8 + 4);
        int rr[8] = { r0.x, r0.y, r0.z, r0.w, r1.x, r1.y, r1.z, r1.w };
#pragma unroll
        for (int j = 0; j < 8; ++j) {
            float v = w_t[rr[j] * B_ + b0 + mc];
            ex[kk][j] = v;
            mx = fmaxf(mx, v);
        }
    }
    mx = fmaxf(mx, __shfl_xor(mx, 16));
    mx = fmaxf(mx, __shfl_xor(mx, 32));
    float s = 0.f;
#pragma unroll
    for (int kk = 0; kk < 4; ++kk)
#pragma unroll
        for (int j = 0; j < 8; ++j) { ex[kk][j] = __expf(ex[kk][j] - mx); s += ex[kk][j]; }
    s += __shfl_xor(s, 16);
    s += __shfl_xor(s, 32);
    float inv = 1.f / s;

    bf16x8 afr[4];
#pragma unroll
    for (int kk = 0; kk < 4; ++kk)
#pragma unroll
        for (int j = 0; j < 8; ++j) afr[kk][j] = (bf16_t)(ex[kk][j] * inv);

    __syncthreads();   // drains vmcnt -> all E/W stages done & visible

    // ---- F-GEMM: 8 n-tiles, K=128, B = staged Eh/El from LDS ----
    f32x4 accF[8];
#pragma unroll
    for (int nn = 0; nn < 8; ++nn) accF[nn] = (f32x4){0.f, 0.f, 0.f, 0.f};
#pragma unroll
    for (int kk = 0; kk < 4; ++kk) {
#pragma unroll
        for (int nn = 0; nn < 8; ++nn) {
            int r = kk * 8 + nn;
            bf16x8 bh = *(const bf16x8*)(bufE + r * 1024 + lane * 16);
            bf16x8 bl = *(const bf16x8*)(bufE + 32768 + r * 1024 + lane * 16);
            accF[nn] = MFMA16(afr[kk], bh, accF[nn]);
            accF[nn] = MFMA16(afr[kk], bl, accF[nn]);
        }
    }

    // ---- LayerNorm 1 (wave-internal): rows q*4+reg ----
    float mu[4], rs[4];
#pragma unroll
    for (int reg = 0; reg < 4; ++reg) {
        float ps = 0.f, pq = 0.f;
#pragma unroll
        for (int nn = 0; nn < 8; ++nn) { float v = accF[nn][reg]; ps += v; pq += v * v; }
#pragma unroll
        for (int o = 1; o <= 8; o <<= 1) { ps += __shfl_xor(ps, o); pq += __shfl_xor(pq, o); }
        float m_ = ps * (1.f / NHID_);
        mu[reg] = m_;
        rs[reg] = rsqrtf(pq * (1.f / NHID_) - m_ * m_ + EPS_);
    }

    __syncthreads();   // all waves' E reads done -> bufE reusable (z + lin2 frags)

    // ---- stage lin2 frags (8 x 1KB rows) into bufE+40960, 1 per wave ----
    {
        const char* src = (wid < 4) ? ((const char*)L2h + wid * 1024)
                                    : ((const char*)L2l + (wid - 4) * 1024);
        char* dst = bufE + 40960 + ((wid < 4) ? wid * 1024
                                              : 4096 + (wid - 4) * 1024);
        GLDS16(src + lane * 16, dst);
    }

    bf16_t* zw = (bf16_t*)bufE + wid * (16 * ZLD);   // per-wave z tile (bf16)

    // ---- z1 = LN1 out (bf16), per-wave region ----
#pragma unroll
    for (int nn = 0; nn < 8; ++nn) {
        int c = nn * 16 + mc;
        float gv = ln1g[c], bv = ln1b[c];
#pragma unroll
        for (int reg = 0; reg < 4; ++reg)
            zw[(q * 4 + reg) * ZLD + c] =
                (bf16_t)((accF[nn][reg] - mu[reg]) * rs[reg] * gv + bv);
    }

    // ---- lin1 GEMM: A from zw, B = staged Wh/Wl from LDS ----
    bf16x8 a2[4];
#pragma unroll
    for (int kk = 0; kk < 4; ++kk)
        a2[kk] = *(const bf16x8*)&zw[mc * ZLD + kk * 32 + q * 8];

    f32x4 accA[8];
#pragma unroll
    for (int nn = 0; nn < 8; ++nn) accA[nn] = (f32x4){0.f, 0.f, 0.f, 0.f};
#pragma unroll
    for (int kk = 0; kk < 4; ++kk) {
#pragma unroll
        for (int nn = 0; nn < 8; ++nn) {
            int r = kk * 8 + nn;
            bf16x8 bh = *(const bf16x8*)(bufW + r * 1024 + lane * 16);
            bf16x8 bl = *(const bf16x8*)(bufW + 32768 + r * 1024 + lane * 16);
            accA[nn] = MFMA16(a2[kk], bh, accA[nn]);
            accA[nn] = MFMA16(a2[kk], bl, accA[nn]);
        }
    }

    // ---- bias + ReLU + LayerNorm 2 (wave-internal) ----
#pragma unroll
    for (int nn = 0; nn < 8; ++nn) {
        float bv = lin1b[nn * 16 + mc];
#pragma unroll
        for (int reg = 0; reg < 4; ++reg)
            accA[nn][reg] = fmaxf(accA[nn][reg] + bv, 0.f);
    }
    float mu2[4], rs2[4];
#pragma unroll
    for (int reg = 0; reg < 4; ++reg) {
        float ps = 0.f, pq = 0.f;
#pragma unroll
        for (int nn = 0; nn < 8; ++nn) { float v = accA[nn][reg]; ps += v; pq += v * v; }
#pragma unroll
        for (int o = 1; o <= 8; o <<= 1) { ps += __shfl_xor(ps, o); pq += __shfl_xor(pq, o); }
        float m_ = ps * (1.f / NHID_);
        mu2[reg] = m_;
        rs2[reg] = rsqrtf(pq * (1.f / NHID_) - m_ * m_ + EPS_);
    }
#pragma unroll
    for (int nn = 0; nn < 8; ++nn) {
        int c = nn * 16 + mc;
        float gv = ln2g[c], bv = ln2b[c];
#pragma unroll
        for (int reg = 0; reg < 4; ++reg)
            zw[(q * 4 + reg) * ZLD + c] =
                (bf16_t)((accA[nn][reg] - mu2[reg]) * rs2[reg] * gv + bv);
    }

    __syncthreads();   // all waves' lin2-frag stages done & visible

    // ---- lin2: 16x128 @ 128x16(padded), B = staged frags from LDS ----
    f32x4 accO = {0.f, 0.f, 0.f, 0.f};
#pragma unroll
    for (int kk = 0; kk < 4; ++kk) {
        bf16x8 a3 = *(const bf16x8*)&zw[mc * ZLD + kk * 32 + q * 8];
        bf16x8 lh = *(const bf16x8*)(bufE + 40960 + kk * 1024 + lane * 16);
        bf16x8 ll = *(const bf16x8*)(bufE + 40960 + 4096 + kk * 1024 + lane * 16);
        accO = MFMA16(a3, lh, accO);
        accO = MFMA16(a3, ll, accO);
    }
    if (mc < NCLASS_) {
#pragma unroll
        for (int reg = 0; reg < 4; ++reg)
            atomicAdd(&acc[(b0 + q * 4 + reg) * NCLASS_ + mc], accO[reg]);
    }
}

// ---------------------------------------------------------------------------
// k_final: out = acc/NFOREST + lin2_b
// ---------------------------------------------------------------------------
__global__ __launch_bounds__(256) void k_final(
    const float* __restrict__ acc, const float* __restrict__ lin2b,
    float* __restrict__ out)
{
    int i = blockIdx.x * 256 + threadIdx.x;
    if (i < B_ * NCLASS_) {
        int c = i % NCLASS_;
        out[i] = acc[i] * (1.f / NFOREST_) + lin2b[c];
    }
}

// ---------------------------------------------------------------------------
extern "C" void kernel_launch(void* const* d_in, const int* in_sizes, int n_in,
                              void* d_out, int out_size, void* d_ws, size_t ws_size,
                              hipStream_t stream)
{
    const float* x     = (const float*)d_in[0];
    const float* w1    = (const float*)d_in[1];
    const float* b1    = (const float*)d_in[2];
    const int*   perm  = (const int*)  d_in[3];
    const float* gn1g  = (const float*)d_in[4];
    const float* gn1b  = (const float*)d_in[5];
    const float* w2a   = (const float*)d_in[6];
    const float* b2a   = (const float*)d_in[7];
    const float* gn2g  = (const float*)d_in[8];
    const float* gn2b  = (const float*)d_in[9];
    const float* w2b   = (const float*)d_in[10];
    const float* b2b   = (const float*)d_in[11];
    const float* E     = (const float*)d_in[12];
    const int*   swr   = (const int*)  d_in[13];
    const float* ln1g  = (const float*)d_in[14];
    const float* ln1b  = (const float*)d_in[15];
    const float* lin1w = (const float*)d_in[16];
    const float* lin1b = (const float*)d_in[17];
    const float* ln2g  = (const float*)d_in[18];
    const float* ln2b  = (const float*)d_in[19];
    const float* lin2w = (const float*)d_in[20];
    const float* lin2b = (const float*)d_in[21];

    char* base = (char*)d_ws;
    float*  w_t  = (float*)base;                                    // 4 MB
    float*  accp = (float*)(base + 4u * 1024 * 1024);               // 40 KB
    float*  x_t  = (float*)(base + 4u * 1024 * 1024 + 64 * 1024);   // 256 KB
    bf16_t* Eh   = (bf16_t*)(base + 4u * 1024 * 1024 + 64 * 1024 + 256 * 1024);
    bf16_t* El   = Eh  + (size_t)EG_FRAGS * 8;
    bf16_t* Wh   = El  + (size_t)EG_FRAGS * 8;
    bf16_t* Wl   = Wh  + (size_t)W1_FRAGS * 8;
    bf16_t* L2h  = Wl  + (size_t)W1_FRAGS * 8;
    bf16_t* L2l  = L2h + (size_t)L2_FRAGS * 8;

    k_prep<<<1105, 256, 0, stream>>>(E, swr, lin1w, lin2w, x,
                                     Eh, El, Wh, Wl, L2h, L2l, x_t, accp);

    k_rodt<<<NRODT_, 256, 0, stream>>>(
        x_t, w1, b1, perm, gn1g, gn1b, w2a, b2a, gn2g, gn2b, w2b, b2b, w_t);

    k_forest<<<NFOREST_ * 8, 512, 0, stream>>>(
        w_t, swr, Eh, El, Wh, Wl, L2h, L2l,
        ln1g, ln1b, lin1b, ln2g, ln2b, accp);

    k_final<<<(B_ * NCLASS_ + 255) / 256, 256, 0, stream>>>(
        accp, lin2b, (float*)d_out);
}

// Round 5
// 150.869 us; speedup vs baseline: 1.1840x; 1.0530x over previous
//
#include <hip/hip_runtime.h>

// DOFEN inference fused pipeline — fp32 I/O, MFMA core.
// Shapes: B=1024, NCOL=NCOND=64, NRODT=1024, D=4, NEST=128, NFOREST=100,
//         NHID=128, NCLASS=10.
//
// Round 12: exact round-7 (44.3 us) structure; ONE change: B-fragment loads
// are batched 16-deep per k-step (bh[8]/bl[8] arrays, loads first, MFMAs
// second).  Evidence r7-r11: kernel is load-LATENCY bound; throughput ~
// waves x outstanding loads.  r7 had 16 waves/CU but VGPR=60 -> ~2-3 loads
// in flight.  Batching under the same (256,4) cap (128 VGPR) gives ~8-12 in
// flight at unchanged occupancy.  No other edits (r8 spill, r9 low-ILP, r10
// wave-halving, r11 1-block/CU all regressed).

#define B_      1024
#define NCOL_   64
#define NCOND_  64
#define NRODT_  1024
#define NEST_   128
#define NFOREST_ 100
#define NHID_   128
#define NCLASS_ 10
#define EPS_    1e-5f

typedef __bf16 bf16_t;
typedef bf16_t bf16x8 __attribute__((ext_vector_type(8)));
typedef float  f32x4  __attribute__((ext_vector_type(4)));

#define MFMA16(a,b,c) __builtin_amdgcn_mfma_f32_16x16x32_bf16(a,b,c,0,0,0)

#define EG_FRAGS   (NFOREST_*4*8*64)   // 204800 frag-rows of 8 bf16
#define W1_FRAGS   (4*8*64)            // 2048
#define L2_FRAGS   (4*64)              // 256

// ---------------------------------------------------------------------------
// k_prep: B-fragment tables (Esel/f, lin1w, lin2w hi/lo) + x_t + acc zero.
// grid = 1105 x 256.
// ---------------------------------------------------------------------------
__global__ __launch_bounds__(256) void k_prep(
    const float* __restrict__ E,     const int*   __restrict__ swr,
    const float* __restrict__ lin1w, const float* __restrict__ lin2w,
    const float* __restrict__ x,
    bf16_t* __restrict__ Eh,  bf16_t* __restrict__ El,
    bf16_t* __restrict__ Wh,  bf16_t* __restrict__ Wl,
    bf16_t* __restrict__ L2h, bf16_t* __restrict__ L2l,
    float*  __restrict__ x_t, float* __restrict__ accz)
{
    int blk = blockIdx.x, tid = threadIdx.x;
    if (blk < 800) {                              // Esel frags: t=(((f*4+kk)*8+nn)*64+lane)
        int t = blk * 256 + tid;
        int lane = t & 63, nn = (t >> 6) & 7, kk = (t >> 9) & 3, f = t >> 11;
        int q = lane >> 4, n = nn * 16 + (lane & 15);
        bf16x8 hi, lo;
#pragma unroll
        for (int j = 0; j < 8; ++j) {
            int e = kk * 32 + q * 8 + j;
            int r = swr[f * NEST_ + e];
            float v = E[r * NHID_ + n];
            bf16_t h = (bf16_t)v;
            hi[j] = h; lo[j] = (bf16_t)(v - (float)h);
        }
        *(bf16x8*)(Eh + (size_t)t * 8) = hi;
        *(bf16x8*)(El + (size_t)t * 8) = lo;
    } else if (blk < 808) {                       // lin1w frags: t=(kk*8+nn)*64+lane
        int t = (blk - 800) * 256 + tid;
        int lane = t & 63, nn = (t >> 6) & 7, kk = t >> 9;
        int q = lane >> 4, n = nn * 16 + (lane & 15);
        bf16x8 hi, lo;
#pragma unroll
        for (int j = 0; j < 8; ++j) {
            int k = kk * 32 + q * 8 + j;
            float v = lin1w[k * NHID_ + n];
            bf16_t h = (bf16_t)v;
            hi[j] = h; lo[j] = (bf16_t)(v - (float)h);
        }
        *(bf16x8*)(Wh + t * 8) = hi;
        *(bf16x8*)(Wl + t * 8) = lo;
    } else if (blk == 808) {                      // lin2w frags (N pad 16): t=kk*64+lane
        int t = tid;
        int lane = t & 63, kk = t >> 6;
        int q = lane >> 4, n = lane & 15;
        bf16x8 hi, lo;
#pragma unroll
        for (int j = 0; j < 8; ++j) {
            int k = kk * 32 + q * 8 + j;
            float v = (n < NCLASS_) ? lin2w[k * NCLASS_ + n] : 0.f;
            bf16_t h = (bf16_t)v;
            hi[j] = h; lo[j] = (bf16_t)(v - (float)h);
        }
        *(bf16x8*)(L2h + t * 8) = hi;
        *(bf16x8*)(L2l + t * 8) = lo;
    } else if (blk < 1065) {                      // x_t[col][b] = x[b][col]
        int t = (blk - 809) * 256 + tid;
        x_t[t] = x[(t & 1023) * NCOL_ + (t >> 10)];
    } else {                                      // zero acc (B*NCLASS = 10240)
        int t = (blk - 1065) * 256 + tid;
        if (t < B_ * NCLASS_) accz[t] = 0.f;
    }
}

// ---------------------------------------------------------------------------
// k_rodt: one g per block (params scalar-uniform); thread handles 4 b's.
// ---------------------------------------------------------------------------
__global__ __launch_bounds__(256) void k_rodt(
    const float* __restrict__ x_t,  const float* __restrict__ w1,
    const float* __restrict__ b1,   const int*  __restrict__ perm,
    const float* __restrict__ gn1g, const float* __restrict__ gn1b,
    const float* __restrict__ w2a,  const float* __restrict__ b2a,
    const float* __restrict__ gn2g, const float* __restrict__ gn2b,
    const float* __restrict__ w2b,  const float* __restrict__ b2b,
    float* __restrict__ w_t)
{
    int g  = blockIdx.x;
    int bq = threadIdx.x * 4;

    int4 p4 = ((const int4*)perm)[g];
    int col[4]  = { p4.x & 63, p4.y & 63, p4.z & 63, p4.w & 63 };
    int cond[4] = { p4.x >> 6, p4.y >> 6, p4.z >> 6, p4.w >> 6 };
    float w1v[4], b1v[4];
#pragma unroll
    for (int j = 0; j < 4; ++j) {
        w1v[j] = w1[col[j] * NCOND_ + cond[j]];
        b1v[j] = b1[col[j] * NCOND_ + cond[j]];
    }
    float4 g1  = ((const float4*)gn1g)[g];
    float4 o1  = ((const float4*)gn1b)[g];
    float4 ba  = ((const float4*)b2a)[g];
    float4 g2  = ((const float4*)gn2g)[g];
    float4 o2  = ((const float4*)gn2b)[g];
    float4 wb4 = ((const float4*)w2b)[g];
    float  bb  = b2b[g];
    float4 wa[4];
    const float4* w2a4 = (const float4*)w2a;
#pragma unroll
    for (int i = 0; i < 4; ++i) wa[i] = w2a4[g * 4 + i];

    float xv[4][4];
#pragma unroll
    for (int j = 0; j < 4; ++j) {
        float4 t = *(const float4*)&x_t[col[j] * B_ + bq];
        xv[j][0] = t.x; xv[j][1] = t.y; xv[j][2] = t.z; xv[j][3] = t.w;
    }

    float outv[4];
#pragma unroll
    for (int bi = 0; bi < 4; ++bi) {
        float v[4];
#pragma unroll
        for (int j = 0; j < 4; ++j) {
            float t = xv[j][bi] * w1v[j] + b1v[j];
            v[j] = 1.0f / (1.0f + __expf(-t));
        }
        float mu = (v[0] + v[1] + v[2] + v[3]) * 0.25f;
        float var = 0.f;
#pragma unroll
        for (int j = 0; j < 4; ++j) { float d = v[j] - mu; var += d * d; }
        var *= 0.25f;
        float rs = rsqrtf(var + EPS_);
        float h[4];
        h[0] = (v[0] - mu) * rs * g1.x + o1.x;
        h[1] = (v[1] - mu) * rs * g1.y + o1.y;
        h[2] = (v[2] - mu) * rs * g1.z + o1.z;
        h[3] = (v[3] - mu) * rs * g1.w + o1.w;

        float4 a = ba;
#pragma unroll
        for (int i = 0; i < 4; ++i) {
            a.x += h[i] * wa[i].x; a.y += h[i] * wa[i].y;
            a.z += h[i] * wa[i].z; a.w += h[i] * wa[i].w;
        }
        float t2[4];
        t2[0] = fmaxf(a.x, 0.f); t2[1] = fmaxf(a.y, 0.f);
        t2[2] = fmaxf(a.z, 0.f); t2[3] = fmaxf(a.w, 0.f);

        float mu2 = (t2[0] + t2[1] + t2[2] + t2[3]) * 0.25f;
        float var2 = 0.f;
#pragma unroll
        for (int j = 0; j < 4; ++j) { float d = t2[j] - mu2; var2 += d * d; }
        var2 *= 0.25f;
        float rs2 = rsqrtf(var2 + EPS_);

        float wvv = bb;
        wvv += ((t2[0] - mu2) * rs2 * g2.x + o2.x) * wb4.x;
        wvv += ((t2[1] - mu2) * rs2 * g2.y + o2.y) * wb4.y;
        wvv += ((t2[2] - mu2) * rs2 * g2.z + o2.z) * wb4.z;
        wvv += ((t2[3] - mu2) * rs2 * g2.w + o2.w) * wb4.w;
        outv[bi] = wvv;
    }
    *(float4*)&w_t[(size_t)g * B_ + bq] = make_float4(outv[0], outv[1], outv[2], outv[3]);
}

// ---------------------------------------------------------------------------
// k_forest: block=(f, 64 batch rows), 4 waves, wave = one 16-row m-tile x
// all 8 n-tiles.  Barrier-free; per-wave 16x132 fp32 LDS z-tile.
// B-fragment loads batched 16-deep per k-step (bh[8]/bl[8]) for MLP.
// lane: q=lane>>4, mc=lane&15.  A: m=mc, k=q*8+j(+32kk).  C: row=q*4+reg,
// col=nn*16+mc.
// ---------------------------------------------------------------------------
__global__ __launch_bounds__(256, 4) void k_forest(
    const float*  __restrict__ w_t, const int* __restrict__ swr,
    const bf16_t* __restrict__ Eh,  const bf16_t* __restrict__ El,
    const bf16_t* __restrict__ Wh,  const bf16_t* __restrict__ Wl,
    const bf16_t* __restrict__ L2h, const bf16_t* __restrict__ L2l,
    const float* __restrict__ ln1g, const float* __restrict__ ln1b,
    const float* __restrict__ lin1b,
    const float* __restrict__ ln2g, const float* __restrict__ ln2b,
    float* __restrict__ acc)
{
    __shared__ float zsh[4][16 * 132];    // per-wave z tile, pad 132

    int tid  = threadIdx.x;
    int wid  = tid >> 6;
    int lane = tid & 63;
    int q    = lane >> 4;
    int mc   = lane & 15;

    int n    = blockIdx.x;
    int swiz = (n & 7) * 200 + (n >> 3);  // co-locate same-f blocks per XCD
    int f    = swiz >> 4;
    int bt   = swiz & 15;
    int b0   = bt * 64 + wid * 16;        // this wave's first batch row

    const int* swrf = swr + f * NEST_;
    float* zw = zsh[wid];

    // ---- softmax in A-frag lanes: ws[m=mc][e=kk*32+q*8+j] ----
    float ex[4][8];
    float mx = -1e30f;
#pragma unroll
    for (int kk = 0; kk < 4; ++kk) {
        int4 r0 = *(const int4*)(swrf + kk * 32 + q * 8);
        int4 r1 = *(const int4*)(swrf + kk * 32 + q * 8 + 4);
        int rr[8] = { r0.x, r0.y, r0.z, r0.w, r1.x, r1.y, r1.z, r1.w };
#pragma unroll
        for (int j = 0; j < 8; ++j) {
            float v = w_t[rr[j] * B_ + b0 + mc];
            ex[kk][j] = v;
            mx = fmaxf(mx, v);
        }
    }
    mx = fmaxf(mx, __shfl_xor(mx, 16));
    mx = fmaxf(mx, __shfl_xor(mx, 32));
    float s = 0.f;
#pragma unroll
    for (int kk = 0; kk < 4; ++kk)
#pragma unroll
        for (int j = 0; j < 8; ++j) { ex[kk][j] = __expf(ex[kk][j] - mx); s += ex[kk][j]; }
    s += __shfl_xor(s, 16);
    s += __shfl_xor(s, 32);
    float inv = 1.f / s;

    bf16x8 afr[4];
#pragma unroll
    for (int kk = 0; kk < 4; ++kk)
#pragma unroll
        for (int j = 0; j < 8; ++j) afr[kk][j] = (bf16_t)(ex[kk][j] * inv);

    // ---- F-GEMM: all 8 n-tiles, K=128, B split hi/lo; loads batched ----
    f32x4 accF[8];
#pragma unroll
    for (int nn = 0; nn < 8; ++nn) accF[nn] = (f32x4){0.f, 0.f, 0.f, 0.f};
    const bf16x8* EHf = (const bf16x8*)Eh;
    const bf16x8* ELf = (const bf16x8*)El;
#pragma unroll
    for (int kk = 0; kk < 4; ++kk) {
        size_t bi = (size_t)(f * 4 + kk) * 8;
        bf16x8 bh[8], bl[8];
#pragma unroll
        for (int nn = 0; nn < 8; ++nn) {
            bh[nn] = EHf[(bi + nn) * 64 + lane];
            bl[nn] = ELf[(bi + nn) * 64 + lane];
        }
#pragma unroll
        for (int nn = 0; nn < 8; ++nn) {
            accF[nn] = MFMA16(afr[kk], bh[nn], accF[nn]);
            accF[nn] = MFMA16(afr[kk], bl[nn], accF[nn]);
        }
    }

    // ---- LayerNorm 1 (wave-internal): rows q*4+reg ----
    float mu[4], rs[4];
#pragma unroll
    for (int reg = 0; reg < 4; ++reg) {
        float ps = 0.f, pq = 0.f;
#pragma unroll
        for (int nn = 0; nn < 8; ++nn) { float v = accF[nn][reg]; ps += v; pq += v * v; }
#pragma unroll
        for (int o = 1; o <= 8; o <<= 1) { ps += __shfl_xor(ps, o); pq += __shfl_xor(pq, o); }
        float m_ = ps * (1.f / NHID_);
        mu[reg] = m_;
        rs[reg] = rsqrtf(pq * (1.f / NHID_) - m_ * m_ + EPS_);
    }
    {
#pragma unroll
        for (int nn = 0; nn < 8; ++nn) {
            int c = nn * 16 + mc;
            float gv = ln1g[c], bv = ln1b[c];
#pragma unroll
            for (int reg = 0; reg < 4; ++reg)
                zw[(q * 4 + reg) * 132 + c] = (accF[nn][reg] - mu[reg]) * rs[reg] * gv + bv;
        }
    }

    // ---- lin1 GEMM: A from zw (single bf16), B = Wh/Wl; loads batched ----
    bf16x8 a2[4];
#pragma unroll
    for (int kk = 0; kk < 4; ++kk) {
        int dwb = kk * 32 + q * 8;
        f32x4 u0 = *(const f32x4*)&zw[mc * 132 + dwb];
        f32x4 u1 = *(const f32x4*)&zw[mc * 132 + dwb + 4];
#pragma unroll
        for (int j = 0; j < 4; ++j) { a2[kk][j] = (bf16_t)u0[j]; a2[kk][4 + j] = (bf16_t)u1[j]; }
    }
    f32x4 accA[8];
#pragma unroll
    for (int nn = 0; nn < 8; ++nn) accA[nn] = (f32x4){0.f, 0.f, 0.f, 0.f};
    const bf16x8* WHf = (const bf16x8*)Wh;
    const bf16x8* WLf = (const bf16x8*)Wl;
#pragma unroll
    for (int kk = 0; kk < 4; ++kk) {
        bf16x8 bh[8], bl[8];
#pragma unroll
        for (int nn = 0; nn < 8; ++nn) {
            bh[nn] = WHf[(kk * 8 + nn) * 64 + lane];
            bl[nn] = WLf[(kk * 8 + nn) * 64 + lane];
        }
#pragma unroll
        for (int nn = 0; nn < 8; ++nn) {
            accA[nn] = MFMA16(a2[kk], bh[nn], accA[nn]);
            accA[nn] = MFMA16(a2[kk], bl[nn], accA[nn]);
        }
    }

    // ---- bias + ReLU + LayerNorm 2 (wave-internal) ----
#pragma unroll
    for (int nn = 0; nn < 8; ++nn) {
        float bv = lin1b[nn * 16 + mc];
#pragma unroll
        for (int reg = 0; reg < 4; ++reg)
            accA[nn][reg] = fmaxf(accA[nn][reg] + bv, 0.f);
    }
    float mu2[4], rs2[4];
#pragma unroll
    for (int reg = 0; reg < 4; ++reg) {
        float ps = 0.f, pq = 0.f;
#pragma unroll
        for (int nn = 0; nn < 8; ++nn) { float v = accA[nn][reg]; ps += v; pq += v * v; }
#pragma unroll
        for (int o = 1; o <= 8; o <<= 1) { ps += __shfl_xor(ps, o); pq += __shfl_xor(pq, o); }
        float m_ = ps * (1.f / NHID_);
        mu2[reg] = m_;
        rs2[reg] = rsqrtf(pq * (1.f / NHID_) - m_ * m_ + EPS_);
    }
    {
#pragma unroll
        for (int nn = 0; nn < 8; ++nn) {
            int c = nn * 16 + mc;
            float gv = ln2g[c], bv = ln2b[c];
#pragma unroll
            for (int reg = 0; reg < 4; ++reg)
                zw[(q * 4 + reg) * 132 + c] = (accA[nn][reg] - mu2[reg]) * rs2[reg] * gv + bv;
        }
    }

    // ---- lin2: 16x128 @ 128x16(padded); loads batched ----
    f32x4 accO = {0.f, 0.f, 0.f, 0.f};
    const bf16x8* LHf = (const bf16x8*)L2h;
    const bf16x8* LLf = (const bf16x8*)L2l;
    {
        bf16x8 lh[4], ll[4];
#pragma unroll
        for (int kk = 0; kk < 4; ++kk) {
            lh[kk] = LHf[kk * 64 + lane];
            ll[kk] = LLf[kk * 64 + lane];
        }
#pragma unroll
        for (int kk = 0; kk < 4; ++kk) {
            int dwb = kk * 32 + q * 8;
            f32x4 u0 = *(const f32x4*)&zw[mc * 132 + dwb];
            f32x4 u1 = *(const f32x4*)&zw[mc * 132 + dwb + 4];
            bf16x8 a3;
#pragma unroll
            for (int j = 0; j < 4; ++j) { a3[j] = (bf16_t)u0[j]; a3[4 + j] = (bf16_t)u1[j]; }
            accO = MFMA16(a3, lh[kk], accO);
            accO = MFMA16(a3, ll[kk], accO);
        }
    }
    if (mc < NCLASS_) {
#pragma unroll
        for (int reg = 0; reg < 4; ++reg)
            atomicAdd(&acc[(b0 + q * 4 + reg) * NCLASS_ + mc], accO[reg]);
    }
}

// ---------------------------------------------------------------------------
// k_final: out = acc/NFOREST + lin2_b
// ---------------------------------------------------------------------------
__global__ __launch_bounds__(256) void k_final(
    const float* __restrict__ acc, const float* __restrict__ lin2b,
    float* __restrict__ out)
{
    int i = blockIdx.x * 256 + threadIdx.x;
    if (i < B_ * NCLASS_) {
        int c = i % NCLASS_;
        out[i] = acc[i] * (1.f / NFOREST_) + lin2b[c];
    }
}

// ---------------------------------------------------------------------------
extern "C" void kernel_launch(void* const* d_in, const int* in_sizes, int n_in,
                              void* d_out, int out_size, void* d_ws, size_t ws_size,
                              hipStream_t stream)
{
    const float* x     = (const float*)d_in[0];
    const float* w1    = (const float*)d_in[1];
    const float* b1    = (const float*)d_in[2];
    const int*   perm  = (const int*)  d_in[3];
    const float* gn1g  = (const float*)d_in[4];
    const float* gn1b  = (const float*)d_in[5];
    const float* w2a   = (const float*)d_in[6];
    const float* b2a   = (const float*)d_in[7];
    const float* gn2g  = (const float*)d_in[8];
    const float* gn2b  = (const float*)d_in[9];
    const float* w2b   = (const float*)d_in[10];
    const float* b2b   = (const float*)d_in[11];
    const float* E     = (const float*)d_in[12];
    const int*   swr   = (const int*)  d_in[13];
    const float* ln1g  = (const float*)d_in[14];
    const float* ln1b  = (const float*)d_in[15];
    const float* lin1w = (const float*)d_in[16];
    const float* lin1b = (const float*)d_in[17];
    const float* ln2g  = (const float*)d_in[18];
    const float* ln2b  = (const float*)d_in[19];
    const float* lin2w = (const float*)d_in[20];
    const float* lin2b = (const float*)d_in[21];

    char* base = (char*)d_ws;
    float*  w_t  = (float*)base;                                    // 4 MB
    float*  accp = (float*)(base + 4u * 1024 * 1024);               // 40 KB
    float*  x_t  = (float*)(base + 4u * 1024 * 1024 + 64 * 1024);   // 256 KB
    bf16_t* Eh   = (bf16_t*)(base + 4u * 1024 * 1024 + 64 * 1024 + 256 * 1024);
    bf16_t* El   = Eh  + (size_t)EG_FRAGS * 8;
    bf16_t* Wh   = El  + (size_t)EG_FRAGS * 8;
    bf16_t* Wl   = Wh  + (size_t)W1_FRAGS * 8;
    bf16_t* L2h  = Wl  + (size_t)W1_FRAGS * 8;
    bf16_t* L2l  = L2h + (size_t)L2_FRAGS * 8;

    k_prep<<<1105, 256, 0, stream>>>(E, swr, lin1w, lin2w, x,
                                     Eh, El, Wh, Wl, L2h, L2l, x_t, accp);

    k_rodt<<<NRODT_, 256, 0, stream>>>(
        x_t, w1, b1, perm, gn1g, gn1b, w2a, b2a, gn2g, gn2b, w2b, b2b, w_t);

    k_forest<<<NFOREST_ * 16, 256, 0, stream>>>(
        w_t, swr, Eh, El, Wh, Wl, L2h, L2l,
        ln1g, ln1b, lin1b, ln2g, ln2b, accp);

    k_final<<<(B_ * NCLASS_ + 255) / 256, 256, 0, stream>>>(
        accp, lin2b, (float*)d_out);
}

// Round 6
// 141.582 us; speedup vs baseline: 1.2617x; 1.0656x over previous
//
#include <hip/hip_runtime.h>

// DOFEN inference fused pipeline — fp32 I/O, MFMA core.
// Shapes: B=1024, NCOL=NCOND=64, NRODT=1024, D=4, NEST=128, NFOREST=100,
//         NHID=128, NCLASS=10.
//
// Round 13: k_forest block-cooperative N-SPLIT.  Block = (f, 64 rows), 4
// waves; each wave computes ALL 64 rows x its 2 n-tiles (nn0=2*wid) for the
// F/lin1 GEMMs.  B-fragments loaded ONCE per block (4x fewer global loads:
// 672 -> ~300/block); A-fragments exchanged through a bf16 LDS panel
// (ds_read_b128, ZLD=136 2-way-free) so no per-wave register growth (acc =
// 32 VGPR).  C tiles exchanged via f32 LDS; LN1/LN2 lanes read exactly the
// values they held in regs before -> bit-identical stats & rounding.
// LDS 51.2 KB -> 3 blocks/CU (12 waves/CU).  4 block-lifetime barriers.
// Evidence r7-r12: latency-bound, throughput ~ waves x loads-in-flight;
// this cuts load count 2.3x at EQUAL-or-better occupancy (r10/r11 cut loads
// but paid VGPR/residency; r12 proved compiler already max-batches).
// k_prep / k_rodt / k_final unchanged (baseline).

#define B_      1024
#define NCOL_   64
#define NCOND_  64
#define NRODT_  1024
#define NEST_   128
#define NFOREST_ 100
#define NHID_   128
#define NCLASS_ 10
#define EPS_    1e-5f

typedef __bf16 bf16_t;
typedef bf16_t bf16x8 __attribute__((ext_vector_type(8)));
typedef float  f32x4  __attribute__((ext_vector_type(4)));

#define MFMA16(a,b,c) __builtin_amdgcn_mfma_f32_16x16x32_bf16(a,b,c,0,0,0)

#define EG_FRAGS   (NFOREST_*4*8*64)   // 204800 frag-rows of 8 bf16
#define W1_FRAGS   (4*8*64)            // 2048
#define L2_FRAGS   (4*64)              // 256

#define ZLD 136                        // bf16 panel row pad: 272B, 16B-aligned

// ---------------------------------------------------------------------------
// k_prep: B-fragment tables (Esel/f, lin1w, lin2w hi/lo) + x_t + acc zero.
// grid = 1105 x 256.
// ---------------------------------------------------------------------------
__global__ __launch_bounds__(256) void k_prep(
    const float* __restrict__ E,     const int*   __restrict__ swr,
    const float* __restrict__ lin1w, const float* __restrict__ lin2w,
    const float* __restrict__ x,
    bf16_t* __restrict__ Eh,  bf16_t* __restrict__ El,
    bf16_t* __restrict__ Wh,  bf16_t* __restrict__ Wl,
    bf16_t* __restrict__ L2h, bf16_t* __restrict__ L2l,
    float*  __restrict__ x_t, float* __restrict__ accz)
{
    int blk = blockIdx.x, tid = threadIdx.x;
    if (blk < 800) {                              // Esel frags: t=(((f*4+kk)*8+nn)*64+lane)
        int t = blk * 256 + tid;
        int lane = t & 63, nn = (t >> 6) & 7, kk = (t >> 9) & 3, f = t >> 11;
        int q = lane >> 4, n = nn * 16 + (lane & 15);
        bf16x8 hi, lo;
#pragma unroll
        for (int j = 0; j < 8; ++j) {
            int e = kk * 32 + q * 8 + j;
            int r = swr[f * NEST_ + e];
            float v = E[r * NHID_ + n];
            bf16_t h = (bf16_t)v;
            hi[j] = h; lo[j] = (bf16_t)(v - (float)h);
        }
        *(bf16x8*)(Eh + (size_t)t * 8) = hi;
        *(bf16x8*)(El + (size_t)t * 8) = lo;
    } else if (blk < 808) {                       // lin1w frags: t=(kk*8+nn)*64+lane
        int t = (blk - 800) * 256 + tid;
        int lane = t & 63, nn = (t >> 6) & 7, kk = t >> 9;
        int q = lane >> 4, n = nn * 16 + (lane & 15);
        bf16x8 hi, lo;
#pragma unroll
        for (int j = 0; j < 8; ++j) {
            int k = kk * 32 + q * 8 + j;
            float v = lin1w[k * NHID_ + n];
            bf16_t h = (bf16_t)v;
            hi[j] = h; lo[j] = (bf16_t)(v - (float)h);
        }
        *(bf16x8*)(Wh + t * 8) = hi;
        *(bf16x8*)(Wl + t * 8) = lo;
    } else if (blk == 808) {                      // lin2w frags (N pad 16): t=kk*64+lane
        int t = tid;
        int lane = t & 63, kk = t >> 6;
        int q = lane >> 4, n = lane & 15;
        bf16x8 hi, lo;
#pragma unroll
        for (int j = 0; j < 8; ++j) {
            int k = kk * 32 + q * 8 + j;
            float v = (n < NCLASS_) ? lin2w[k * NCLASS_ + n] : 0.f;
            bf16_t h = (bf16_t)v;
            hi[j] = h; lo[j] = (bf16_t)(v - (float)h);
        }
        *(bf16x8*)(L2h + t * 8) = hi;
        *(bf16x8*)(L2l + t * 8) = lo;
    } else if (blk < 1065) {                      // x_t[col][b] = x[b][col]
        int t = (blk - 809) * 256 + tid;
        x_t[t] = x[(t & 1023) * NCOL_ + (t >> 10)];
    } else {                                      // zero acc (B*NCLASS = 10240)
        int t = (blk - 1065) * 256 + tid;
        if (t < B_ * NCLASS_) accz[t] = 0.f;
    }
}

// ---------------------------------------------------------------------------
// k_rodt: one g per block (params scalar-uniform); thread handles 4 b's.
// ---------------------------------------------------------------------------
__global__ __launch_bounds__(256) void k_rodt(
    const float* __restrict__ x_t,  const float* __restrict__ w1,
    const float* __restrict__ b1,   const int*  __restrict__ perm,
    const float* __restrict__ gn1g, const float* __restrict__ gn1b,
    const float* __restrict__ w2a,  const float* __restrict__ b2a,
    const float* __restrict__ gn2g, const float* __restrict__ gn2b,
    const float* __restrict__ w2b,  const float* __restrict__ b2b,
    float* __restrict__ w_t)
{
    int g  = blockIdx.x;
    int bq = threadIdx.x * 4;

    int4 p4 = ((const int4*)perm)[g];
    int col[4]  = { p4.x & 63, p4.y & 63, p4.z & 63, p4.w & 63 };
    int cond[4] = { p4.x >> 6, p4.y >> 6, p4.z >> 6, p4.w >> 6 };
    float w1v[4], b1v[4];
#pragma unroll
    for (int j = 0; j < 4; ++j) {
        w1v[j] = w1[col[j] * NCOND_ + cond[j]];
        b1v[j] = b1[col[j] * NCOND_ + cond[j]];
    }
    float4 g1  = ((const float4*)gn1g)[g];
    float4 o1  = ((const float4*)gn1b)[g];
    float4 ba  = ((const float4*)b2a)[g];
    float4 g2  = ((const float4*)gn2g)[g];
    float4 o2  = ((const float4*)gn2b)[g];
    float4 wb4 = ((const float4*)w2b)[g];
    float  bb  = b2b[g];
    float4 wa[4];
    const float4* w2a4 = (const float4*)w2a;
#pragma unroll
    for (int i = 0; i < 4; ++i) wa[i] = w2a4[g * 4 + i];

    float xv[4][4];
#pragma unroll
    for (int j = 0; j < 4; ++j) {
        float4 t = *(const float4*)&x_t[col[j] * B_ + bq];
        xv[j][0] = t.x; xv[j][1] = t.y; xv[j][2] = t.z; xv[j][3] = t.w;
    }

    float outv[4];
#pragma unroll
    for (int bi = 0; bi < 4; ++bi) {
        float v[4];
#pragma unroll
        for (int j = 0; j < 4; ++j) {
            float t = xv[j][bi] * w1v[j] + b1v[j];
            v[j] = 1.0f / (1.0f + __expf(-t));
        }
        float mu = (v[0] + v[1] + v[2] + v[3]) * 0.25f;
        float var = 0.f;
#pragma unroll
        for (int j = 0; j < 4; ++j) { float d = v[j] - mu; var += d * d; }
        var *= 0.25f;
        float rs = rsqrtf(var + EPS_);
        float h[4];
        h[0] = (v[0] - mu) * rs * g1.x + o1.x;
        h[1] = (v[1] - mu) * rs * g1.y + o1.y;
        h[2] = (v[2] - mu) * rs * g1.z + o1.z;
        h[3] = (v[3] - mu) * rs * g1.w + o1.w;

        float4 a = ba;
#pragma unroll
        for (int i = 0; i < 4; ++i) {
            a.x += h[i] * wa[i].x; a.y += h[i] * wa[i].y;
            a.z += h[i] * wa[i].z; a.w += h[i] * wa[i].w;
        }
        float t2[4];
        t2[0] = fmaxf(a.x, 0.f); t2[1] = fmaxf(a.y, 0.f);
        t2[2] = fmaxf(a.z, 0.f); t2[3] = fmaxf(a.w, 0.f);

        float mu2 = (t2[0] + t2[1] + t2[2] + t2[3]) * 0.25f;
        float var2 = 0.f;
#pragma unroll
        for (int j = 0; j < 4; ++j) { float d = t2[j] - mu2; var2 += d * d; }
        var2 *= 0.25f;
        float rs2 = rsqrtf(var2 + EPS_);

        float wvv = bb;
        wvv += ((t2[0] - mu2) * rs2 * g2.x + o2.x) * wb4.x;
        wvv += ((t2[1] - mu2) * rs2 * g2.y + o2.y) * wb4.y;
        wvv += ((t2[2] - mu2) * rs2 * g2.z + o2.z) * wb4.z;
        wvv += ((t2[3] - mu2) * rs2 * g2.w + o2.w) * wb4.w;
        outv[bi] = wvv;
    }
    *(float4*)&w_t[(size_t)g * B_ + bq] = make_float4(outv[0], outv[1], outv[2], outv[3]);
}

// ---------------------------------------------------------------------------
// k_forest: block = (f, 64 rows), 4 waves.  N-split GEMMs: wave computes ALL
// 64 rows x n-tiles {2*wid, 2*wid+1}; B-frags loaded once per block.
// A-panel zb (bf16 [64][ZLD]) carries ws -> z1 -> z2; C-panel zC (f32
// [64][132]) exchanges GEMM outputs for the LNs.  LN lanes read exactly the
// values they formerly held in accF/accA -> bit-identical reductions.
// lane: q=lane>>4, mc=lane&15.  A row m=(mt*16+)mc, k=kk*32+q*8+j.
// C: row=(mt*16+)q*4+reg, col=nn*16+mc.
// ---------------------------------------------------------------------------
__global__ __launch_bounds__(256) void k_forest(
    const float*  __restrict__ w_t, const int* __restrict__ swr,
    const bf16_t* __restrict__ Eh,  const bf16_t* __restrict__ El,
    const bf16_t* __restrict__ Wh,  const bf16_t* __restrict__ Wl,
    const bf16_t* __restrict__ L2h, const bf16_t* __restrict__ L2l,
    const float* __restrict__ ln1g, const float* __restrict__ ln1b,
    const float* __restrict__ lin1b,
    const float* __restrict__ ln2g, const float* __restrict__ ln2b,
    float* __restrict__ acc)
{
    __shared__ __align__(16) float  zC[64 * 132];   // 33792 B: GEMM C exchange
    __shared__ __align__(16) bf16_t zb[64 * ZLD];   // 17408 B: ws -> z1 -> z2

    int tid  = threadIdx.x;
    int wid  = tid >> 6;
    int lane = tid & 63;
    int q    = lane >> 4;
    int mc   = lane & 15;

    int n    = blockIdx.x;
    int swiz = (n & 7) * 200 + (n >> 3);  // co-locate same-f blocks per XCD
    int f    = swiz >> 4;
    int bt   = swiz & 15;
    int b0   = bt * 64 + wid * 16;        // this wave's softmax/output rows

    const int* swrf = swr + f * NEST_;
    int nn0 = wid * 2;                    // this wave's n-tiles

    // ---- softmax rows [b0,b0+16): ws[m=mc][e=kk*32+q*8+j] (as in r7) ----
    float ex[4][8];
    float mx = -1e30f;
#pragma unroll
    for (int kk = 0; kk < 4; ++kk) {
        int4 r0 = *(const int4*)(swrf + kk * 32 + q * 8);
        int4 r1 = *(const int4*)(swrf + kk * 32 + q * 8 + 4);
        int rr[8] = { r0.x, r0.y, r0.z, r0.w, r1.x, r1.y, r1.z, r1.w };
#pragma unroll
        for (int j = 0; j < 8; ++j) {
            float v = w_t[rr[j] * B_ + b0 + mc];
            ex[kk][j] = v;
            mx = fmaxf(mx, v);
        }
    }
    mx = fmaxf(mx, __shfl_xor(mx, 16));
    mx = fmaxf(mx, __shfl_xor(mx, 32));
    float s = 0.f;
#pragma unroll
    for (int kk = 0; kk < 4; ++kk)
#pragma unroll
        for (int j = 0; j < 8; ++j) { ex[kk][j] = __expf(ex[kk][j] - mx); s += ex[kk][j]; }
    s += __shfl_xor(s, 16);
    s += __shfl_xor(s, 32);
    float inv = 1.f / s;

    // write ws into A-panel: row (in block) = wid*16+mc, k = kk*32+q*8+j
#pragma unroll
    for (int kk = 0; kk < 4; ++kk) {
        bf16x8 v;
#pragma unroll
        for (int j = 0; j < 8; ++j) v[j] = (bf16_t)(ex[kk][j] * inv);
        *(bf16x8*)&zb[(wid * 16 + mc) * ZLD + kk * 32 + q * 8] = v;
    }

    __syncthreads();   // B1: ws complete

    // ---- F-GEMM: all 64 rows x 2 n-tiles, B-frags loaded once/block ----
    const bf16x8* EHf = (const bf16x8*)Eh;
    const bf16x8* ELf = (const bf16x8*)El;
    f32x4 accF[4][2];
#pragma unroll
    for (int mt = 0; mt < 4; ++mt) {
        accF[mt][0] = (f32x4){0.f, 0.f, 0.f, 0.f};
        accF[mt][1] = (f32x4){0.f, 0.f, 0.f, 0.f};
    }
#pragma unroll
    for (int kk = 0; kk < 4; ++kk) {
        size_t bi = (size_t)(f * 4 + kk) * 8;
        bf16x8 bh0 = EHf[(bi + nn0) * 64 + lane];
        bf16x8 bh1 = EHf[(bi + nn0 + 1) * 64 + lane];
        bf16x8 bl0 = ELf[(bi + nn0) * 64 + lane];
        bf16x8 bl1 = ELf[(bi + nn0 + 1) * 64 + lane];
        bf16x8 av[4];
#pragma unroll
        for (int mt = 0; mt < 4; ++mt)
            av[mt] = *(const bf16x8*)&zb[(mt * 16 + mc) * ZLD + kk * 32 + q * 8];
#pragma unroll
        for (int mt = 0; mt < 4; ++mt) {
            accF[mt][0] = MFMA16(av[mt], bh0, accF[mt][0]);
            accF[mt][1] = MFMA16(av[mt], bh1, accF[mt][1]);
            accF[mt][0] = MFMA16(av[mt], bl0, accF[mt][0]);
            accF[mt][1] = MFMA16(av[mt], bl1, accF[mt][1]);
        }
    }
    // C -> zC: row = mt*16+q*4+reg, col = (nn0+nj)*16+mc
#pragma unroll
    for (int mt = 0; mt < 4; ++mt)
#pragma unroll
        for (int nj = 0; nj < 2; ++nj)
#pragma unroll
            for (int reg = 0; reg < 4; ++reg)
                zC[(mt * 16 + q * 4 + reg) * 132 + (nn0 + nj) * 16 + mc] = accF[mt][nj][reg];

    __syncthreads();   // B2: F complete

    // ---- LayerNorm 1 on own rows (wid*16 + q*4+reg): identical math ----
    {
        float vv[8][4];
#pragma unroll
        for (int nn = 0; nn < 8; ++nn)
#pragma unroll
            for (int reg = 0; reg < 4; ++reg)
                vv[nn][reg] = zC[(wid * 16 + q * 4 + reg) * 132 + nn * 16 + mc];
        float mu[4], rs[4];
#pragma unroll
        for (int reg = 0; reg < 4; ++reg) {
            float ps = 0.f, pq = 0.f;
#pragma unroll
            for (int nn = 0; nn < 8; ++nn) { float v = vv[nn][reg]; ps += v; pq += v * v; }
#pragma unroll
            for (int o = 1; o <= 8; o <<= 1) { ps += __shfl_xor(ps, o); pq += __shfl_xor(pq, o); }
            float m_ = ps * (1.f / NHID_);
            mu[reg] = m_;
            rs[reg] = rsqrtf(pq * (1.f / NHID_) - m_ * m_ + EPS_);
        }
#pragma unroll
        for (int nn = 0; nn < 8; ++nn) {
            int c = nn * 16 + mc;
            float gv = ln1g[c], bv = ln1b[c];
#pragma unroll
            for (int reg = 0; reg < 4; ++reg)
                zb[(wid * 16 + q * 4 + reg) * ZLD + c] =
                    (bf16_t)((vv[nn][reg] - mu[reg]) * rs[reg] * gv + bv);
        }
    }

    __syncthreads();   // B3: z1 complete

    // ---- lin1 GEMM: all 64 rows x 2 n-tiles ----
    const bf16x8* WHf = (const bf16x8*)Wh;
    const bf16x8* WLf = (const bf16x8*)Wl;
    f32x4 accA[4][2];
#pragma unroll
    for (int mt = 0; mt < 4; ++mt) {
        accA[mt][0] = (f32x4){0.f, 0.f, 0.f, 0.f};
        accA[mt][1] = (f32x4){0.f, 0.f, 0.f, 0.f};
    }
#pragma unroll
    for (int kk = 0; kk < 4; ++kk) {
        bf16x8 bh0 = WHf[(kk * 8 + nn0) * 64 + lane];
        bf16x8 bh1 = WHf[(kk * 8 + nn0 + 1) * 64 + lane];
        bf16x8 bl0 = WLf[(kk * 8 + nn0) * 64 + lane];
        bf16x8 bl1 = WLf[(kk * 8 + nn0 + 1) * 64 + lane];
        bf16x8 av[4];
#pragma unroll
        for (int mt = 0; mt < 4; ++mt)
            av[mt] = *(const bf16x8*)&zb[(mt * 16 + mc) * ZLD + kk * 32 + q * 8];
#pragma unroll
        for (int mt = 0; mt < 4; ++mt) {
            accA[mt][0] = MFMA16(av[mt], bh0, accA[mt][0]);
            accA[mt][1] = MFMA16(av[mt], bh1, accA[mt][1]);
            accA[mt][0] = MFMA16(av[mt], bl0, accA[mt][0]);
            accA[mt][1] = MFMA16(av[mt], bl1, accA[mt][1]);
        }
    }

    __syncthreads();   // B4a: all z1 reads done -> zC reusable
#pragma unroll
    for (int mt = 0; mt < 4; ++mt)
#pragma unroll
        for (int nj = 0; nj < 2; ++nj)
#pragma unroll
            for (int reg = 0; reg < 4; ++reg)
                zC[(mt * 16 + q * 4 + reg) * 132 + (nn0 + nj) * 16 + mc] = accA[mt][nj][reg];

    __syncthreads();   // B4: lin1 C complete

    // ---- bias + ReLU + LayerNorm 2 on own rows; z2 -> zb own rows ----
    {
        float vv[8][4];
#pragma unroll
        for (int nn = 0; nn < 8; ++nn) {
            float bv = lin1b[nn * 16 + mc];
#pragma unroll
            for (int reg = 0; reg < 4; ++reg)
                vv[nn][reg] = fmaxf(
                    zC[(wid * 16 + q * 4 + reg) * 132 + nn * 16 + mc] + bv, 0.f);
        }
        float mu2[4], rs2[4];
#pragma unroll
        for (int reg = 0; reg < 4; ++reg) {
            float ps = 0.f, pq = 0.f;
#pragma unroll
            for (int nn = 0; nn < 8; ++nn) { float v = vv[nn][reg]; ps += v; pq += v * v; }
#pragma unroll
            for (int o = 1; o <= 8; o <<= 1) { ps += __shfl_xor(ps, o); pq += __shfl_xor(pq, o); }
            float m_ = ps * (1.f / NHID_);
            mu2[reg] = m_;
            rs2[reg] = rsqrtf(pq * (1.f / NHID_) - m_ * m_ + EPS_);
        }
#pragma unroll
        for (int nn = 0; nn < 8; ++nn) {
            int c = nn * 16 + mc;
            float gv = ln2g[c], bv = ln2b[c];
#pragma unroll
            for (int reg = 0; reg < 4; ++reg)
                zb[(wid * 16 + q * 4 + reg) * ZLD + c] =
                    (bf16_t)((vv[nn][reg] - mu2[reg]) * rs2[reg] * gv + bv);
        }
    }
    // z2 rows [wid*16, wid*16+16) written & read by this wave only -> no barrier

    // ---- lin2: own 16 rows, 16x128 @ 128x16(padded) ----
    f32x4 accO = {0.f, 0.f, 0.f, 0.f};
    const bf16x8* LHf = (const bf16x8*)L2h;
    const bf16x8* LLf = (const bf16x8*)L2l;
#pragma unroll
    for (int kk = 0; kk < 4; ++kk) {
        bf16x8 a3 = *(const bf16x8*)&zb[(wid * 16 + mc) * ZLD + kk * 32 + q * 8];
        accO = MFMA16(a3, LHf[kk * 64 + lane], accO);
        accO = MFMA16(a3, LLf[kk * 64 + lane], accO);
    }
    if (mc < NCLASS_) {
#pragma unroll
        for (int reg = 0; reg < 4; ++reg)
            atomicAdd(&acc[(b0 + q * 4 + reg) * NCLASS_ + mc], accO[reg]);
    }
}

// ---------------------------------------------------------------------------
// k_final: out = acc/NFOREST + lin2_b
// ---------------------------------------------------------------------------
__global__ __launch_bounds__(256) void k_final(
    const float* __restrict__ acc, const float* __restrict__ lin2b,
    float* __restrict__ out)
{
    int i = blockIdx.x * 256 + threadIdx.x;
    if (i < B_ * NCLASS_) {
        int c = i % NCLASS_;
        out[i] = acc[i] * (1.f / NFOREST_) + lin2b[c];
    }
}

// ---------------------------------------------------------------------------
extern "C" void kernel_launch(void* const* d_in, const int* in_sizes, int n_in,
                              void* d_out, int out_size, void* d_ws, size_t ws_size,
                              hipStream_t stream)
{
    const float* x     = (const float*)d_in[0];
    const float* w1    = (const float*)d_in[1];
    const float* b1    = (const float*)d_in[2];
    const int*   perm  = (const int*)  d_in[3];
    const float* gn1g  = (const float*)d_in[4];
    const float* gn1b  = (const float*)d_in[5];
    const float* w2a   = (const float*)d_in[6];
    const float* b2a   = (const float*)d_in[7];
    const float* gn2g  = (const float*)d_in[8];
    const float* gn2b  = (const float*)d_in[9];
    const float* w2b   = (const float*)d_in[10];
    const float* b2b   = (const float*)d_in[11];
    const float* E     = (const float*)d_in[12];
    const int*   swr   = (const int*)  d_in[13];
    const float* ln1g  = (const float*)d_in[14];
    const float* ln1b  = (const float*)d_in[15];
    const float* lin1w = (const float*)d_in[16];
    const float* lin1b = (const float*)d_in[17];
    const float* ln2g  = (const float*)d_in[18];
    const float* ln2b  = (const float*)d_in[19];
    const float* lin2w = (const float*)d_in[20];
    const float* lin2b = (const float*)d_in[21];

    char* base = (char*)d_ws;
    float*  w_t  = (float*)base;                                    // 4 MB
    float*  accp = (float*)(base + 4u * 1024 * 1024);               // 40 KB
    float*  x_t  = (float*)(base + 4u * 1024 * 1024 + 64 * 1024);   // 256 KB
    bf16_t* Eh   = (bf16_t*)(base + 4u * 1024 * 1024 + 64 * 1024 + 256 * 1024);
    bf16_t* El   = Eh  + (size_t)EG_FRAGS * 8;
    bf16_t* Wh   = El  + (size_t)EG_FRAGS * 8;
    bf16_t* Wl   = Wh  + (size_t)W1_FRAGS * 8;
    bf16_t* L2h  = Wl  + (size_t)W1_FRAGS * 8;
    bf16_t* L2l  = L2h + (size_t)L2_FRAGS * 8;

    k_prep<<<1105, 256, 0, stream>>>(E, swr, lin1w, lin2w, x,
                                     Eh, El, Wh, Wl, L2h, L2l, x_t, accp);

    k_rodt<<<NRODT_, 256, 0, stream>>>(
        x_t, w1, b1, perm, gn1g, gn1b, w2a, b2a, gn2g, gn2b, w2b, b2b, w_t);

    k_forest<<<NFOREST_ * 16, 256, 0, stream>>>(
        w_t, swr, Eh, El, Wh, Wl, L2h, L2l,
        ln1g, ln1b, lin1b, ln2g, ln2b, accp);

    k_final<<<(B_ * NCLASS_ + 255) / 256, 256, 0, stream>>>(
        accp, lin2b, (float*)d_out);
}

// Round 7
// 139.520 us; speedup vs baseline: 1.2804x; 1.0148x over previous
//
#include <hip/hip_runtime.h>

// DOFEN inference fused pipeline — fp32 I/O, MFMA core.
// Shapes: B=1024, NCOL=NCOND=64, NRODT=1024, D=4, NEST=128, NFOREST=100,
//         NHID=128, NCLASS=10.
//
// Round 14: r13 N-split structure + cross-barrier register PREFETCH.
// Each GEMM phase's B-fragments are issued during the PREVIOUS phase
// (addresses depend only on f/nn0/lane): E-frags during softmax, W-frags
// during F-epilogue/LN1, lin2-frags during LN2.  The compiler's mandatory
// vmcnt(0) drain at each __syncthreads becomes the wait point; VALU work
// (exp/shuffle/LN) covers the ~300cy L2 latency that previously started
// every phase cold.  launch_bounds(256,3): VGPR cap 170, peak ~150, 3
// blocks/CU (LDS-capped) preserved.  Math/rounding order unchanged.
// History: r8 (256,8) spill disaster; r9 VGPR-48 no-ILP; r10 wave-halving;
// r11 128KB-LDS 1-block/CU; r12 source batching = neutral (compiler already
// batches); r13 N-split B-frags once/block = win (forest ~44 -> ~35).

#define B_      1024
#define NCOL_   64
#define NCOND_  64
#define NRODT_  1024
#define NEST_   128
#define NFOREST_ 100
#define NHID_   128
#define NCLASS_ 10
#define EPS_    1e-5f

typedef __bf16 bf16_t;
typedef bf16_t bf16x8 __attribute__((ext_vector_type(8)));
typedef float  f32x4  __attribute__((ext_vector_type(4)));

#define MFMA16(a,b,c) __builtin_amdgcn_mfma_f32_16x16x32_bf16(a,b,c,0,0,0)

#define EG_FRAGS   (NFOREST_*4*8*64)   // 204800 frag-rows of 8 bf16
#define W1_FRAGS   (4*8*64)            // 2048
#define L2_FRAGS   (4*64)              // 256

#define ZLD 136                        // bf16 panel row pad: 272B, 16B-aligned

// ---------------------------------------------------------------------------
// k_prep: B-fragment tables (Esel/f, lin1w, lin2w hi/lo) + x_t + acc zero.
// grid = 1105 x 256.
// ---------------------------------------------------------------------------
__global__ __launch_bounds__(256) void k_prep(
    const float* __restrict__ E,     const int*   __restrict__ swr,
    const float* __restrict__ lin1w, const float* __restrict__ lin2w,
    const float* __restrict__ x,
    bf16_t* __restrict__ Eh,  bf16_t* __restrict__ El,
    bf16_t* __restrict__ Wh,  bf16_t* __restrict__ Wl,
    bf16_t* __restrict__ L2h, bf16_t* __restrict__ L2l,
    float*  __restrict__ x_t, float* __restrict__ accz)
{
    int blk = blockIdx.x, tid = threadIdx.x;
    if (blk < 800) {                              // Esel frags: t=(((f*4+kk)*8+nn)*64+lane)
        int t = blk * 256 + tid;
        int lane = t & 63, nn = (t >> 6) & 7, kk = (t >> 9) & 3, f = t >> 11;
        int q = lane >> 4, n = nn * 16 + (lane & 15);
        bf16x8 hi, lo;
#pragma unroll
        for (int j = 0; j < 8; ++j) {
            int e = kk * 32 + q * 8 + j;
            int r = swr[f * NEST_ + e];
            float v = E[r * NHID_ + n];
            bf16_t h = (bf16_t)v;
            hi[j] = h; lo[j] = (bf16_t)(v - (float)h);
        }
        *(bf16x8*)(Eh + (size_t)t * 8) = hi;
        *(bf16x8*)(El + (size_t)t * 8) = lo;
    } else if (blk < 808) {                       // lin1w frags: t=(kk*8+nn)*64+lane
        int t = (blk - 800) * 256 + tid;
        int lane = t & 63, nn = (t >> 6) & 7, kk = t >> 9;
        int q = lane >> 4, n = nn * 16 + (lane & 15);
        bf16x8 hi, lo;
#pragma unroll
        for (int j = 0; j < 8; ++j) {
            int k = kk * 32 + q * 8 + j;
            float v = lin1w[k * NHID_ + n];
            bf16_t h = (bf16_t)v;
            hi[j] = h; lo[j] = (bf16_t)(v - (float)h);
        }
        *(bf16x8*)(Wh + t * 8) = hi;
        *(bf16x8*)(Wl + t * 8) = lo;
    } else if (blk == 808) {                      // lin2w frags (N pad 16): t=kk*64+lane
        int t = tid;
        int lane = t & 63, kk = t >> 6;
        int q = lane >> 4, n = lane & 15;
        bf16x8 hi, lo;
#pragma unroll
        for (int j = 0; j < 8; ++j) {
            int k = kk * 32 + q * 8 + j;
            float v = (n < NCLASS_) ? lin2w[k * NCLASS_ + n] : 0.f;
            bf16_t h = (bf16_t)v;
            hi[j] = h; lo[j] = (bf16_t)(v - (float)h);
        }
        *(bf16x8*)(L2h + t * 8) = hi;
        *(bf16x8*)(L2l + t * 8) = lo;
    } else if (blk < 1065) {                      // x_t[col][b] = x[b][col]
        int t = (blk - 809) * 256 + tid;
        x_t[t] = x[(t & 1023) * NCOL_ + (t >> 10)];
    } else {                                      // zero acc (B*NCLASS = 10240)
        int t = (blk - 1065) * 256 + tid;
        if (t < B_ * NCLASS_) accz[t] = 0.f;
    }
}

// ---------------------------------------------------------------------------
// k_rodt: one g per block (params scalar-uniform); thread handles 4 b's.
// ---------------------------------------------------------------------------
__global__ __launch_bounds__(256) void k_rodt(
    const float* __restrict__ x_t,  const float* __restrict__ w1,
    const float* __restrict__ b1,   const int*  __restrict__ perm,
    const float* __restrict__ gn1g, const float* __restrict__ gn1b,
    const float* __restrict__ w2a,  const float* __restrict__ b2a,
    const float* __restrict__ gn2g, const float* __restrict__ gn2b,
    const float* __restrict__ w2b,  const float* __restrict__ b2b,
    float* __restrict__ w_t)
{
    int g  = blockIdx.x;
    int bq = threadIdx.x * 4;

    int4 p4 = ((const int4*)perm)[g];
    int col[4]  = { p4.x & 63, p4.y & 63, p4.z & 63, p4.w & 63 };
    int cond[4] = { p4.x >> 6, p4.y >> 6, p4.z >> 6, p4.w >> 6 };
    float w1v[4], b1v[4];
#pragma unroll
    for (int j = 0; j < 4; ++j) {
        w1v[j] = w1[col[j] * NCOND_ + cond[j]];
        b1v[j] = b1[col[j] * NCOND_ + cond[j]];
    }
    float4 g1  = ((const float4*)gn1g)[g];
    float4 o1  = ((const float4*)gn1b)[g];
    float4 ba  = ((const float4*)b2a)[g];
    float4 g2  = ((const float4*)gn2g)[g];
    float4 o2  = ((const float4*)gn2b)[g];
    float4 wb4 = ((const float4*)w2b)[g];
    float  bb  = b2b[g];
    float4 wa[4];
    const float4* w2a4 = (const float4*)w2a;
#pragma unroll
    for (int i = 0; i < 4; ++i) wa[i] = w2a4[g * 4 + i];

    float xv[4][4];
#pragma unroll
    for (int j = 0; j < 4; ++j) {
        float4 t = *(const float4*)&x_t[col[j] * B_ + bq];
        xv[j][0] = t.x; xv[j][1] = t.y; xv[j][2] = t.z; xv[j][3] = t.w;
    }

    float outv[4];
#pragma unroll
    for (int bi = 0; bi < 4; ++bi) {
        float v[4];
#pragma unroll
        for (int j = 0; j < 4; ++j) {
            float t = xv[j][bi] * w1v[j] + b1v[j];
            v[j] = 1.0f / (1.0f + __expf(-t));
        }
        float mu = (v[0] + v[1] + v[2] + v[3]) * 0.25f;
        float var = 0.f;
#pragma unroll
        for (int j = 0; j < 4; ++j) { float d = v[j] - mu; var += d * d; }
        var *= 0.25f;
        float rs = rsqrtf(var + EPS_);
        float h[4];
        h[0] = (v[0] - mu) * rs * g1.x + o1.x;
        h[1] = (v[1] - mu) * rs * g1.y + o1.y;
        h[2] = (v[2] - mu) * rs * g1.z + o1.z;
        h[3] = (v[3] - mu) * rs * g1.w + o1.w;

        float4 a = ba;
#pragma unroll
        for (int i = 0; i < 4; ++i) {
            a.x += h[i] * wa[i].x; a.y += h[i] * wa[i].y;
            a.z += h[i] * wa[i].z; a.w += h[i] * wa[i].w;
        }
        float t2[4];
        t2[0] = fmaxf(a.x, 0.f); t2[1] = fmaxf(a.y, 0.f);
        t2[2] = fmaxf(a.z, 0.f); t2[3] = fmaxf(a.w, 0.f);

        float mu2 = (t2[0] + t2[1] + t2[2] + t2[3]) * 0.25f;
        float var2 = 0.f;
#pragma unroll
        for (int j = 0; j < 4; ++j) { float d = t2[j] - mu2; var2 += d * d; }
        var2 *= 0.25f;
        float rs2 = rsqrtf(var2 + EPS_);

        float wvv = bb;
        wvv += ((t2[0] - mu2) * rs2 * g2.x + o2.x) * wb4.x;
        wvv += ((t2[1] - mu2) * rs2 * g2.y + o2.y) * wb4.y;
        wvv += ((t2[2] - mu2) * rs2 * g2.z + o2.z) * wb4.z;
        wvv += ((t2[3] - mu2) * rs2 * g2.w + o2.w) * wb4.w;
        outv[bi] = wvv;
    }
    *(float4*)&w_t[(size_t)g * B_ + bq] = make_float4(outv[0], outv[1], outv[2], outv[3]);
}

// ---------------------------------------------------------------------------
// k_forest: block = (f, 64 rows), 4 waves.  N-split GEMMs (r13) + phase
// prefetch (r14).  Wave computes ALL 64 rows x n-tiles {2wid, 2wid+1};
// B-frags loaded once per block, PREFETCHED one phase early into regs.
// A-panel zb (bf16 [64][ZLD]); C-panel zC (f32 [64][132]).
// lane: q=lane>>4, mc=lane&15.  A row m=(mt*16+)mc, k=kk*32+q*8+j.
// C: row=(mt*16+)q*4+reg, col=nn*16+mc.
// ---------------------------------------------------------------------------
__global__ __launch_bounds__(256, 3) void k_forest(
    const float*  __restrict__ w_t, const int* __restrict__ swr,
    const bf16_t* __restrict__ Eh,  const bf16_t* __restrict__ El,
    const bf16_t* __restrict__ Wh,  const bf16_t* __restrict__ Wl,
    const bf16_t* __restrict__ L2h, const bf16_t* __restrict__ L2l,
    const float* __restrict__ ln1g, const float* __restrict__ ln1b,
    const float* __restrict__ lin1b,
    const float* __restrict__ ln2g, const float* __restrict__ ln2b,
    float* __restrict__ acc)
{
    __shared__ __align__(16) float  zC[64 * 132];   // 33792 B: GEMM C exchange
    __shared__ __align__(16) bf16_t zb[64 * ZLD];   // 17408 B: ws -> z1 -> z2

    int tid  = threadIdx.x;
    int wid  = tid >> 6;
    int lane = tid & 63;
    int q    = lane >> 4;
    int mc   = lane & 15;

    int n    = blockIdx.x;
    int swiz = (n & 7) * 200 + (n >> 3);  // co-locate same-f blocks per XCD
    int f    = swiz >> 4;
    int bt   = swiz & 15;
    int b0   = bt * 64 + wid * 16;        // this wave's softmax/output rows

    const int* swrf = swr + f * NEST_;
    int nn0 = wid * 2;                    // this wave's n-tiles

    const bf16x8* EHf = (const bf16x8*)Eh;
    const bf16x8* ELf = (const bf16x8*)El;
    const bf16x8* WHf = (const bf16x8*)Wh;
    const bf16x8* WLf = (const bf16x8*)Wl;
    const bf16x8* LHf = (const bf16x8*)L2h;
    const bf16x8* LLf = (const bf16x8*)L2l;

    // ---- softmax rows [b0,b0+16): ws[m=mc][e=kk*32+q*8+j] ----
    float ex[4][8];
    float mx = -1e30f;
#pragma unroll
    for (int kk = 0; kk < 4; ++kk) {
        int4 r0 = *(const int4*)(swrf + kk * 32 + q * 8);
        int4 r1 = *(const int4*)(swrf + kk * 32 + q * 8 + 4);
        int rr[8] = { r0.x, r0.y, r0.z, r0.w, r1.x, r1.y, r1.z, r1.w };
#pragma unroll
        for (int j = 0; j < 8; ++j) {
            float v = w_t[rr[j] * B_ + b0 + mc];
            ex[kk][j] = v;
            mx = fmaxf(mx, v);
        }
    }

    // PREFETCH E-frags (issued behind the w_t gather; drained at B1 while
    // the exp/shuffle work below runs).  pe[kk] = {h(nn0), h(nn0+1),
    // l(nn0), l(nn0+1)}.
    bf16x8 pe[4][4];
#pragma unroll
    for (int kk = 0; kk < 4; ++kk) {
        size_t bi = (size_t)(f * 4 + kk) * 8;
        pe[kk][0] = EHf[(bi + nn0) * 64 + lane];
        pe[kk][1] = EHf[(bi + nn0 + 1) * 64 + lane];
        pe[kk][2] = ELf[(bi + nn0) * 64 + lane];
        pe[kk][3] = ELf[(bi + nn0 + 1) * 64 + lane];
    }

    mx = fmaxf(mx, __shfl_xor(mx, 16));
    mx = fmaxf(mx, __shfl_xor(mx, 32));
    float s = 0.f;
#pragma unroll
    for (int kk = 0; kk < 4; ++kk)
#pragma unroll
        for (int j = 0; j < 8; ++j) { ex[kk][j] = __expf(ex[kk][j] - mx); s += ex[kk][j]; }
    s += __shfl_xor(s, 16);
    s += __shfl_xor(s, 32);
    float inv = 1.f / s;

    // write ws into A-panel: row = wid*16+mc, k = kk*32+q*8+j
#pragma unroll
    for (int kk = 0; kk < 4; ++kk) {
        bf16x8 v;
#pragma unroll
        for (int j = 0; j < 8; ++j) v[j] = (bf16_t)(ex[kk][j] * inv);
        *(bf16x8*)&zb[(wid * 16 + mc) * ZLD + kk * 32 + q * 8] = v;
    }

    __syncthreads();   // B1: ws complete (also drains E prefetch)

    // ---- F-GEMM: all 64 rows x 2 n-tiles, B from prefetched regs ----
    f32x4 accF[4][2];
#pragma unroll
    for (int mt = 0; mt < 4; ++mt) {
        accF[mt][0] = (f32x4){0.f, 0.f, 0.f, 0.f};
        accF[mt][1] = (f32x4){0.f, 0.f, 0.f, 0.f};
    }
#pragma unroll
    for (int kk = 0; kk < 4; ++kk) {
        bf16x8 av[4];
#pragma unroll
        for (int mt = 0; mt < 4; ++mt)
            av[mt] = *(const bf16x8*)&zb[(mt * 16 + mc) * ZLD + kk * 32 + q * 8];
#pragma unroll
        for (int mt = 0; mt < 4; ++mt) {
            accF[mt][0] = MFMA16(av[mt], pe[kk][0], accF[mt][0]);
            accF[mt][1] = MFMA16(av[mt], pe[kk][1], accF[mt][1]);
            accF[mt][0] = MFMA16(av[mt], pe[kk][2], accF[mt][0]);
            accF[mt][1] = MFMA16(av[mt], pe[kk][3], accF[mt][1]);
        }
    }

    // PREFETCH W-frags (drained at B3; LN1 VALU below covers latency).
    bf16x8 pw[4][4];
#pragma unroll
    for (int kk = 0; kk < 4; ++kk) {
        pw[kk][0] = WHf[(kk * 8 + nn0) * 64 + lane];
        pw[kk][1] = WHf[(kk * 8 + nn0 + 1) * 64 + lane];
        pw[kk][2] = WLf[(kk * 8 + nn0) * 64 + lane];
        pw[kk][3] = WLf[(kk * 8 + nn0 + 1) * 64 + lane];
    }

    // C -> zC: row = mt*16+q*4+reg, col = (nn0+nj)*16+mc
#pragma unroll
    for (int mt = 0; mt < 4; ++mt)
#pragma unroll
        for (int nj = 0; nj < 2; ++nj)
#pragma unroll
            for (int reg = 0; reg < 4; ++reg)
                zC[(mt * 16 + q * 4 + reg) * 132 + (nn0 + nj) * 16 + mc] = accF[mt][nj][reg];

    __syncthreads();   // B2: F complete

    // ---- LayerNorm 1 on own rows (wid*16 + q*4+reg) ----
    {
        float vv[8][4];
#pragma unroll
        for (int nn = 0; nn < 8; ++nn)
#pragma unroll
            for (int reg = 0; reg < 4; ++reg)
                vv[nn][reg] = zC[(wid * 16 + q * 4 + reg) * 132 + nn * 16 + mc];
        float mu[4], rs[4];
#pragma unroll
        for (int reg = 0; reg < 4; ++reg) {
            float ps = 0.f, pq = 0.f;
#pragma unroll
            for (int nn = 0; nn < 8; ++nn) { float v = vv[nn][reg]; ps += v; pq += v * v; }
#pragma unroll
            for (int o = 1; o <= 8; o <<= 1) { ps += __shfl_xor(ps, o); pq += __shfl_xor(pq, o); }
            float m_ = ps * (1.f / NHID_);
            mu[reg] = m_;
            rs[reg] = rsqrtf(pq * (1.f / NHID_) - m_ * m_ + EPS_);
        }
#pragma unroll
        for (int nn = 0; nn < 8; ++nn) {
            int c = nn * 16 + mc;
            float gv = ln1g[c], bv = ln1b[c];
#pragma unroll
            for (int reg = 0; reg < 4; ++reg)
                zb[(wid * 16 + q * 4 + reg) * ZLD + c] =
                    (bf16_t)((vv[nn][reg] - mu[reg]) * rs[reg] * gv + bv);
        }
    }

    __syncthreads();   // B3: z1 complete (also drains W prefetch)

    // ---- lin1 GEMM: all 64 rows x 2 n-tiles, B from prefetched regs ----
    f32x4 accA[4][2];
#pragma unroll
    for (int mt = 0; mt < 4; ++mt) {
        accA[mt][0] = (f32x4){0.f, 0.f, 0.f, 0.f};
        accA[mt][1] = (f32x4){0.f, 0.f, 0.f, 0.f};
    }
#pragma unroll
    for (int kk = 0; kk < 4; ++kk) {
        bf16x8 av[4];
#pragma unroll
        for (int mt = 0; mt < 4; ++mt)
            av[mt] = *(const bf16x8*)&zb[(mt * 16 + mc) * ZLD + kk * 32 + q * 8];
#pragma unroll
        for (int mt = 0; mt < 4; ++mt) {
            accA[mt][0] = MFMA16(av[mt], pw[kk][0], accA[mt][0]);
            accA[mt][1] = MFMA16(av[mt], pw[kk][1], accA[mt][1]);
            accA[mt][0] = MFMA16(av[mt], pw[kk][2], accA[mt][0]);
            accA[mt][1] = MFMA16(av[mt], pw[kk][3], accA[mt][1]);
        }
    }

    __syncthreads();   // B4a: all z1 reads done -> zC reusable
#pragma unroll
    for (int mt = 0; mt < 4; ++mt)
#pragma unroll
        for (int nj = 0; nj < 2; ++nj)
#pragma unroll
            for (int reg = 0; reg < 4; ++reg)
                zC[(mt * 16 + q * 4 + reg) * 132 + (nn0 + nj) * 16 + mc] = accA[mt][nj][reg];

    // PREFETCH lin2 frags (hot in L2, small; drained at B4).
    bf16x8 pl2[4][2];
#pragma unroll
    for (int kk = 0; kk < 4; ++kk) {
        pl2[kk][0] = LHf[kk * 64 + lane];
        pl2[kk][1] = LLf[kk * 64 + lane];
    }

    __syncthreads();   // B4: lin1 C complete

    // ---- bias + ReLU + LayerNorm 2 on own rows; z2 -> zb own rows ----
    {
        float vv[8][4];
#pragma unroll
        for (int nn = 0; nn < 8; ++nn) {
            float bv = lin1b[nn * 16 + mc];
#pragma unroll
            for (int reg = 0; reg < 4; ++reg)
                vv[nn][reg] = fmaxf(
                    zC[(wid * 16 + q * 4 + reg) * 132 + nn * 16 + mc] + bv, 0.f);
        }
        float mu2[4], rs2[4];
#pragma unroll
        for (int reg = 0; reg < 4; ++reg) {
            float ps = 0.f, pq = 0.f;
#pragma unroll
            for (int nn = 0; nn < 8; ++nn) { float v = vv[nn][reg]; ps += v; pq += v * v; }
#pragma unroll
            for (int o = 1; o <= 8; o <<= 1) { ps += __shfl_xor(ps, o); pq += __shfl_xor(pq, o); }
            float m_ = ps * (1.f / NHID_);
            mu2[reg] = m_;
            rs2[reg] = rsqrtf(pq * (1.f / NHID_) - m_ * m_ + EPS_);
        }
#pragma unroll
        for (int nn = 0; nn < 8; ++nn) {
            int c = nn * 16 + mc;
            float gv = ln2g[c], bv = ln2b[c];
#pragma unroll
            for (int reg = 0; reg < 4; ++reg)
                zb[(wid * 16 + q * 4 + reg) * ZLD + c] =
                    (bf16_t)((vv[nn][reg] - mu2[reg]) * rs2[reg] * gv + bv);
        }
    }
    // z2 rows [wid*16, wid*16+16) written & read by this wave only -> no barrier

    // ---- lin2: own 16 rows, 16x128 @ 128x16(padded) ----
    f32x4 accO = {0.f, 0.f, 0.f, 0.f};
#pragma unroll
    for (int kk = 0; kk < 4; ++kk) {
        bf16x8 a3 = *(const bf16x8*)&zb[(wid * 16 + mc) * ZLD + kk * 32 + q * 8];
        accO = MFMA16(a3, pl2[kk][0], accO);
        accO = MFMA16(a3, pl2[kk][1], accO);
    }
    if (mc < NCLASS_) {
#pragma unroll
        for (int reg = 0; reg < 4; ++reg)
            atomicAdd(&acc[(b0 + q * 4 + reg) * NCLASS_ + mc], accO[reg]);
    }
}

// ---------------------------------------------------------------------------
// k_final: out = acc/NFOREST + lin2_b
// ---------------------------------------------------------------------------
__global__ __launch_bounds__(256) void k_final(
    const float* __restrict__ acc, const float* __restrict__ lin2b,
    float* __restrict__ out)
{
    int i = blockIdx.x * 256 + threadIdx.x;
    if (i < B_ * NCLASS_) {
        int c = i % NCLASS_;
        out[i] = acc[i] * (1.f / NFOREST_) + lin2b[c];
    }
}

// ---------------------------------------------------------------------------
extern "C" void kernel_launch(void* const* d_in, const int* in_sizes, int n_in,
                              void* d_out, int out_size, void* d_ws, size_t ws_size,
                              hipStream_t stream)
{
    const float* x     = (const float*)d_in[0];
    const float* w1    = (const float*)d_in[1];
    const float* b1    = (const float*)d_in[2];
    const int*   perm  = (const int*)  d_in[3];
    const float* gn1g  = (const float*)d_in[4];
    const float* gn1b  = (const float*)d_in[5];
    const float* w2a   = (const float*)d_in[6];
    const float* b2a   = (const float*)d_in[7];
    const float* gn2g  = (const float*)d_in[8];
    const float* gn2b  = (const float*)d_in[9];
    const float* w2b   = (const float*)d_in[10];
    const float* b2b   = (const float*)d_in[11];
    const float* E     = (const float*)d_in[12];
    const int*   swr   = (const int*)  d_in[13];
    const float* ln1g  = (const float*)d_in[14];
    const float* ln1b  = (const float*)d_in[15];
    const float* lin1w = (const float*)d_in[16];
    const float* lin1b = (const float*)d_in[17];
    const float* ln2g  = (const float*)d_in[18];
    const float* ln2b  = (const float*)d_in[19];
    const float* lin2w = (const float*)d_in[20];
    const float* lin2b = (const float*)d_in[21];

    char* base = (char*)d_ws;
    float*  w_t  = (float*)base;                                    // 4 MB
    float*  accp = (float*)(base + 4u * 1024 * 1024);               // 40 KB
    float*  x_t  = (float*)(base + 4u * 1024 * 1024 + 64 * 1024);   // 256 KB
    bf16_t* Eh   = (bf16_t*)(base + 4u * 1024 * 1024 + 64 * 1024 + 256 * 1024);
    bf16_t* El   = Eh  + (size_t)EG_FRAGS * 8;
    bf16_t* Wh   = El  + (size_t)EG_FRAGS * 8;
    bf16_t* Wl   = Wh  + (size_t)W1_FRAGS * 8;
    bf16_t* L2h  = Wl  + (size_t)W1_FRAGS * 8;
    bf16_t* L2l  = L2h + (size_t)L2_FRAGS * 8;

    k_prep<<<1105, 256, 0, stream>>>(E, swr, lin1w, lin2w, x,
                                     Eh, El, Wh, Wl, L2h, L2l, x_t, accp);

    k_rodt<<<NRODT_, 256, 0, stream>>>(
        x_t, w1, b1, perm, gn1g, gn1b, w2a, b2a, gn2g, gn2b, w2b, b2b, w_t);

    k_forest<<<NFOREST_ * 16, 256, 0, stream>>>(
        w_t, swr, Eh, El, Wh, Wl, L2h, L2l,
        ln1g, ln1b, lin1b, ln2g, ln2b, accp);

    k_final<<<(B_ * NCLASS_ + 255) / 256, 256, 0, stream>>>(
        accp, lin2b, (float*)d_out);
}